// Round 1
// baseline (5474.109 us; speedup 1.0000x reference)
//
#include <hip/hip_runtime.h>
#include <hip/hip_bf16.h>

#define N_NODES 20000
#define N_EDGES 320000
#define NGRAPH  64
#define FPD     65

// ---------------- degree / norm ----------------
__global__ void init_deg(float* deg) {
    int i = blockIdx.x * blockDim.x + threadIdx.x;
    if (i < N_NODES) deg[i] = 1.0f;   // self-loop
}
__global__ void count_deg(const int* __restrict__ dst, float* deg) {
    int e = blockIdx.x * blockDim.x + threadIdx.x;
    if (e < N_EDGES) atomicAdd(&deg[dst[e]], 1.0f);
}
__global__ void deg_to_dis(float* deg) {
    int i = blockIdx.x * blockDim.x + threadIdx.x;
    if (i < N_NODES) {
        float d = deg[i];
        deg[i] = (d > 0.0f) ? rsqrtf(d) : 0.0f;
    }
}

// ---------------- utility ----------------
__global__ void zero_f32(float* p, long long n) {
    long long i = (long long)blockIdx.x * blockDim.x + threadIdx.x;
    if (i < n) p[i] = 0.0f;
}

// ---------------- fp32 tiled GEMM: C[M,Nc] = A[M,K] @ B[K,Nc] ----------------
// Requires: K % 16 == 0, Nc % 64 == 0. M guarded.
#define BM 64
#define BN 64
#define BK 16
__global__ __launch_bounds__(256) void gemm_f32(
    const float* __restrict__ A, const float* __restrict__ B,
    float* __restrict__ C, int M, int K, int Nc)
{
    __shared__ float As[BK][BM + 4];
    __shared__ float Bs[BK][BN + 4];
    int tid = threadIdx.x;
    int tx = tid & 15, ty = tid >> 4;
    int bm = blockIdx.x * BM;
    int bn = blockIdx.y * BN;

    // A loader: thread -> (row la_r in tile, 4 consecutive k at la_k)
    int la_r = tid >> 2;          // 0..63
    int la_k = (tid & 3) << 2;    // 0,4,8,12
    // B loader: thread -> (k-row lb_r, 4 consecutive cols at lb_c)
    int lb_r = tid >> 4;          // 0..15
    int lb_c = (tid & 15) << 2;   // 0..60

    float acc[4][4] = {};

    for (int k0 = 0; k0 < K; k0 += BK) {
        int gr = bm + la_r;
        float4 av = make_float4(0.f, 0.f, 0.f, 0.f);
        if (gr < M) av = *(const float4*)(A + (size_t)gr * K + k0 + la_k);
        As[la_k + 0][la_r] = av.x;
        As[la_k + 1][la_r] = av.y;
        As[la_k + 2][la_r] = av.z;
        As[la_k + 3][la_r] = av.w;

        float4 bv = *(const float4*)(B + (size_t)(k0 + lb_r) * Nc + bn + lb_c);
        *(float4*)&Bs[lb_r][lb_c] = bv;

        __syncthreads();
        #pragma unroll
        for (int kk = 0; kk < BK; ++kk) {
            float4 a = *(const float4*)&As[kk][ty << 2];
            float4 b = *(const float4*)&Bs[kk][tx << 2];
            acc[0][0] += a.x * b.x; acc[0][1] += a.x * b.y; acc[0][2] += a.x * b.z; acc[0][3] += a.x * b.w;
            acc[1][0] += a.y * b.x; acc[1][1] += a.y * b.y; acc[1][2] += a.y * b.z; acc[1][3] += a.y * b.w;
            acc[2][0] += a.z * b.x; acc[2][1] += a.z * b.y; acc[2][2] += a.z * b.z; acc[2][3] += a.z * b.w;
            acc[3][0] += a.w * b.x; acc[3][1] += a.w * b.y; acc[3][2] += a.w * b.z; acc[3][3] += a.w * b.w;
        }
        __syncthreads();
    }

    #pragma unroll
    for (int i = 0; i < 4; ++i) {
        int row = bm + (ty << 2) + i;
        if (row < M) {
            float4 v = make_float4(acc[i][0], acc[i][1], acc[i][2], acc[i][3]);
            *(float4*)(C + (size_t)row * Nc + bn + (tx << 2)) = v;
        }
    }
}

// ---------------- edge scatter: agg[dst] += h[src] * norm ----------------
// blockIdx.x in [0, E+N): e<E real edges, e>=E self-loops.
__global__ __launch_bounds__(256) void scatter_edges(
    const float* __restrict__ h, float* __restrict__ agg,
    const int* __restrict__ src, const int* __restrict__ dst,
    const float* __restrict__ dis, int Df)
{
    int e = blockIdx.x;
    int s, d; float w;
    if (e < N_EDGES) {
        s = src[e]; d = dst[e];
        w = dis[s] * dis[d];
    } else {
        int i = e - N_EDGES;
        s = d = i;
        float di = dis[i];
        w = di * di;
    }
    const float* hp = h + (size_t)s * Df;
    float* ap = agg + (size_t)d * Df;
    for (int f = threadIdx.x; f < Df; f += blockDim.x)
        atomicAdd(ap + f, hp[f] * w);
}

__global__ void bias_relu(float* x, const float* __restrict__ bias, int Df, int do_relu) {
    int n = blockIdx.x;
    float* p = x + (size_t)n * Df;
    for (int f = threadIdx.x; f < Df; f += blockDim.x) {
        float v = p[f] + bias[f];
        p[f] = do_relu ? fmaxf(v, 0.0f) : v;
    }
}

// ---------------- mean pool over graphs ----------------
__global__ void pool_accum(const float* __restrict__ x, const int* __restrict__ batch,
                           float* pool, float* cnt) {
    int n = blockIdx.x;
    int g = batch[n];
    if (threadIdx.x == 0) atomicAdd(&cnt[g], 1.0f);
    for (int f = threadIdx.x; f < 320; f += blockDim.x)
        atomicAdd(&pool[g * 320 + f], x[(size_t)n * 320 + f]);
}
__global__ void pool_div(float* pool, const float* __restrict__ cnt) {
    int g = blockIdx.x;
    float c = fmaxf(cnt[g], 1.0f);
    for (int f = threadIdx.x; f < 320; f += blockDim.x)
        pool[g * 320 + f] /= c;
}

// ---------------- small MLP layers (M=64 rows) ----------------
__global__ void mlp_linear(const float* __restrict__ in, const float* __restrict__ W,
                           const float* __restrict__ b, float* __restrict__ out,
                           int M, int K, int Nc, int do_relu) {
    int idx = blockIdx.x * blockDim.x + threadIdx.x;
    if (idx >= M * Nc) return;
    int m = idx / Nc, c = idx % Nc;
    float s = b[c];
    const float* ip = in + (size_t)m * K;
    for (int k = 0; k < K; ++k) s += ip[k] * W[(size_t)k * Nc + c];
    out[idx] = do_relu ? fmaxf(s, 0.0f) : s;
}

__global__ void concat_k(const float* __restrict__ fp, const float* __restrict__ xt,
                         float* __restrict__ xc) {
    int idx = blockIdx.x * blockDim.x + threadIdx.x;
    if (idx >= NGRAPH * 193) return;
    int g = idx / 193, j = idx % 193;
    xc[idx] = (j < FPD) ? fp[g * FPD + j] : xt[g * 128 + (j - FPD)];
}

extern "C" void kernel_launch(void* const* d_in, const int* in_sizes, int n_in,
                              void* d_out, int out_size, void* d_ws, size_t ws_size,
                              hipStream_t stream) {
    const float* x    = (const float*)d_in[0];
    const int*   eidx = (const int*)d_in[1];
    const int*   batch= (const int*)d_in[2];
    const float* fp_x = (const float*)d_in[3];
    const float* W1 = (const float*)d_in[4];  const float* b1 = (const float*)d_in[5];
    const float* W2 = (const float*)d_in[6];  const float* b2 = (const float*)d_in[7];
    const float* W3 = (const float*)d_in[8];  const float* b3 = (const float*)d_in[9];
    const float* Wg1= (const float*)d_in[10]; const float* bg1= (const float*)d_in[11];
    const float* Wg2= (const float*)d_in[12]; const float* bg2= (const float*)d_in[13];
    const float* Wf1= (const float*)d_in[14]; const float* bf1= (const float*)d_in[15];
    const float* Wf2= (const float*)d_in[16]; const float* bf2= (const float*)d_in[17];
    const float* Wo = (const float*)d_in[18]; const float* bo = (const float*)d_in[19];
    float* out = (float*)d_out;

    const int* src = eidx;
    const int* dst = eidx + N_EDGES;

    // workspace layout (floats)
    float* ws  = (float*)d_ws;
    float* dis = ws;                                   // 20480 (deg then dis)
    float* h   = dis + 20480;                          // 25,600,000
    float* agg = h + (size_t)N_NODES * 1280;           // 25,600,000
    float* pool= agg + (size_t)N_NODES * 1280;         // 20480
    float* cnt = pool + NGRAPH * 320;                  // 64
    float* m1  = cnt + 64;                             // 64*1024
    float* m2  = m1 + NGRAPH * 1024;                   // 64*128
    float* xc  = m2 + NGRAPH * 128;                    // 64*193
    float* f1  = xc + NGRAPH * 193 + 3;                // 64*1024 (pad to 16B)
    float* f2  = f1 + NGRAPH * 1024;                   // 64*512

    // ---- degrees / symmetric norm ----
    init_deg<<<(N_NODES + 255) / 256, 256, 0, stream>>>(dis);
    count_deg<<<(N_EDGES + 255) / 256, 256, 0, stream>>>(dst, dis);
    deg_to_dis<<<(N_NODES + 255) / 256, 256, 0, stream>>>(dis);

    // ---- layer 1: h = x@W1 ; agg = S h ; relu(agg + b1) ----
    {
        dim3 g((N_NODES + BM - 1) / BM, 1280 / BN);
        gemm_f32<<<g, 256, 0, stream>>>(x, W1, h, N_NODES, 1280, 1280);
        long long tot = (long long)N_NODES * 1280;
        zero_f32<<<(unsigned)((tot + 255) / 256), 256, 0, stream>>>(agg, tot);
        scatter_edges<<<N_EDGES + N_NODES, 256, 0, stream>>>(h, agg, src, dst, dis, 1280);
        bias_relu<<<N_NODES, 256, 0, stream>>>(agg, b1, 1280, 1);
    }
    // ---- layer 2: h = agg@W2 (640) ----
    {
        dim3 g((N_NODES + BM - 1) / BM, 640 / BN);
        gemm_f32<<<g, 256, 0, stream>>>(agg, W2, h, N_NODES, 1280, 640);
        long long tot = (long long)N_NODES * 640;
        zero_f32<<<(unsigned)((tot + 255) / 256), 256, 0, stream>>>(agg, tot);
        scatter_edges<<<N_EDGES + N_NODES, 256, 0, stream>>>(h, agg, src, dst, dis, 640);
        bias_relu<<<N_NODES, 256, 0, stream>>>(agg, b2, 640, 1);
    }
    // ---- layer 3: h = agg@W3 (320) ----
    {
        dim3 g((N_NODES + BM - 1) / BM, 320 / BN);
        gemm_f32<<<g, 256, 0, stream>>>(agg, W3, h, N_NODES, 640, 320);
        long long tot = (long long)N_NODES * 320;
        zero_f32<<<(unsigned)((tot + 255) / 256), 256, 0, stream>>>(agg, tot);
        scatter_edges<<<N_EDGES + N_NODES, 256, 0, stream>>>(h, agg, src, dst, dis, 320);
        bias_relu<<<N_NODES, 256, 0, stream>>>(agg, b3, 320, 1);
    }

    // ---- global mean pool ----
    {
        long long tot = NGRAPH * 320 + 64;
        zero_f32<<<(unsigned)((tot + 255) / 256), 256, 0, stream>>>(pool, tot); // pool+cnt contiguous
        pool_accum<<<N_NODES, 256, 0, stream>>>(agg, batch, pool, cnt);
        pool_div<<<NGRAPH, 256, 0, stream>>>(pool, cnt);
    }

    // ---- MLP head ----
    mlp_linear<<<(NGRAPH * 1024 + 255) / 256, 256, 0, stream>>>(pool, Wg1, bg1, m1, NGRAPH, 320, 1024, 1);
    mlp_linear<<<(NGRAPH * 128 + 255) / 256, 256, 0, stream>>>(m1, Wg2, bg2, m2, NGRAPH, 1024, 128, 0);
    concat_k<<<(NGRAPH * 193 + 255) / 256, 256, 0, stream>>>(fp_x, m2, xc);
    mlp_linear<<<(NGRAPH * 1024 + 255) / 256, 256, 0, stream>>>(xc, Wf1, bf1, f1, NGRAPH, 193, 1024, 1);
    mlp_linear<<<(NGRAPH * 512 + 255) / 256, 256, 0, stream>>>(f1, Wf2, bf2, f2, NGRAPH, 1024, 512, 1);
    mlp_linear<<<1, 256, 0, stream>>>(f2, Wo, bo, out, NGRAPH, 512, 1, 0);
}

// Round 2
// 4196.146 us; speedup vs baseline: 1.3046x; 1.3046x over previous
//
#include <hip/hip_runtime.h>
#include <hip/hip_bf16.h>

#define N_NODES 20000
#define N_EDGES 320000
#define NGRAPH  64
#define FPD     65

typedef __attribute__((ext_vector_type(8))) __bf16 bf16x8;
typedef __attribute__((ext_vector_type(4))) float floatx4;

// ---------------- degree / norm ----------------
__global__ void init_deg(float* deg) {
    int i = blockIdx.x * blockDim.x + threadIdx.x;
    if (i < N_NODES) deg[i] = 1.0f;   // self-loop
}
__global__ void count_deg(const int* __restrict__ dst, float* deg) {
    int e = blockIdx.x * blockDim.x + threadIdx.x;
    if (e < N_EDGES) atomicAdd(&deg[dst[e]], 1.0f);
}
__global__ void deg_to_dis(float* deg) {
    int i = blockIdx.x * blockDim.x + threadIdx.x;
    if (i < N_NODES) {
        float d = deg[i];
        deg[i] = (d > 0.0f) ? rsqrtf(d) : 0.0f;
    }
}

// ---------------- utility ----------------
__global__ void zero_f32(float* p, long long n) {
    long long i = (long long)blockIdx.x * blockDim.x + threadIdx.x;
    if (i < n) p[i] = 0.0f;
}

// f32 -> bf16 (RNE), 4 elements/thread, n % 4 == 0
__global__ void conv_f32_bf16(const float* __restrict__ in, ushort* __restrict__ out, long long n) {
    long long i = ((long long)blockIdx.x * blockDim.x + threadIdx.x) * 4;
    if (i >= n) return;
    float4 v = *(const float4*)(in + i);
    __hip_bfloat16 a = __float2bfloat16(v.x);
    __hip_bfloat16 b = __float2bfloat16(v.y);
    __hip_bfloat16 c = __float2bfloat16(v.z);
    __hip_bfloat16 d = __float2bfloat16(v.w);
    ushort4 o;
    o.x = *(ushort*)&a; o.y = *(ushort*)&b; o.z = *(ushort*)&c; o.w = *(ushort*)&d;
    *(ushort4*)(out + i) = o;
}

// W[K][Nc] f32 -> Wt[Nc][K] bf16. K,Nc % 32 == 0. block (32,8), grid (K/32, Nc/32)
__global__ void transpose_conv(const float* __restrict__ W, ushort* __restrict__ Wt, int K, int Nc) {
    __shared__ float t[32][33];
    int k0 = blockIdx.x * 32, n0 = blockIdx.y * 32;
    int tx = threadIdx.x, ty = threadIdx.y;
    #pragma unroll
    for (int i = 0; i < 4; ++i)
        t[ty + i * 8][tx] = W[(size_t)(k0 + ty + i * 8) * Nc + n0 + tx];
    __syncthreads();
    #pragma unroll
    for (int i = 0; i < 4; ++i) {
        __hip_bfloat16 h = __float2bfloat16(t[tx][ty + i * 8]);
        Wt[(size_t)(n0 + ty + i * 8) * K + k0 + tx] = *(ushort*)&h;
    }
}

// ---------------- bf16 MFMA GEMM: C[M,Nc] = A[M,K] @ Bt[Nc,K]^T ----------------
// A row-major bf16 [M][K], Bt row-major bf16 [Nc][K]. K%32==0, Nc%64==0, M guarded.
// Tile 256x64x32. 256 threads = 4 waves; wave w owns rows [w*64, w*64+64).
#define APAD 40   // LDS row stride in bf16 ((r*5)%8 bank-group pattern -> 2-way, free)
__global__ __launch_bounds__(256) void gemm_bf16(
    const ushort* __restrict__ A, const ushort* __restrict__ Bt,
    float* __restrict__ C, int M, int K, int Nc)
{
    __shared__ ushort As[256 * APAD];
    __shared__ ushort Bs[64 * APAD];
    const int tid = threadIdx.x;
    const int wid = tid >> 6, lane = tid & 63;
    const int quad = lane >> 4, mr = lane & 15;
    const int bm = blockIdx.x * 256, bn = blockIdx.y * 64;

    floatx4 acc[4][4];
    #pragma unroll
    for (int i = 0; i < 4; ++i)
        #pragma unroll
        for (int j = 0; j < 4; ++j)
            acc[i][j] = (floatx4){0.f, 0.f, 0.f, 0.f};

    for (int k0 = 0; k0 < K; k0 += 32) {
        // stage A: 256 rows x 32 bf16 = 1024 x 16B chunks
        #pragma unroll
        for (int it = 0; it < 4; ++it) {
            int idx = tid + it * 256;
            int row = idx >> 2, q = idx & 3;
            int gr = bm + row;
            int4 v = make_int4(0, 0, 0, 0);
            if (gr < M) v = *(const int4*)(A + (size_t)gr * K + k0 + q * 8);
            *(int4*)&As[row * APAD + q * 8] = v;
        }
        // stage B: 64 rows (n) x 32 bf16
        {
            int row = tid >> 2, q = tid & 3;
            int4 v = *(const int4*)(Bt + (size_t)(bn + row) * K + k0 + q * 8);
            *(int4*)&Bs[row * APAD + q * 8] = v;
        }
        __syncthreads();

        bf16x8 af[4], bfv[4];
        #pragma unroll
        for (int t = 0; t < 4; ++t)
            af[t] = *(const bf16x8*)&As[(wid * 64 + t * 16 + mr) * APAD + quad * 8];
        #pragma unroll
        for (int t = 0; t < 4; ++t)
            bfv[t] = *(const bf16x8*)&Bs[(t * 16 + mr) * APAD + quad * 8];

        #pragma unroll
        for (int tm = 0; tm < 4; ++tm)
            #pragma unroll
            for (int tn = 0; tn < 4; ++tn)
                acc[tm][tn] = __builtin_amdgcn_mfma_f32_16x16x32_bf16(af[tm], bfv[tn], acc[tm][tn], 0, 0, 0);
        __syncthreads();
    }

    // C/D layout: col = lane&15, row = quad*4 + reg
    #pragma unroll
    for (int tm = 0; tm < 4; ++tm) {
        int rowb = bm + wid * 64 + tm * 16 + quad * 4;
        #pragma unroll
        for (int r = 0; r < 4; ++r) {
            int row = rowb + r;
            if (row < M) {
                #pragma unroll
                for (int tn = 0; tn < 4; ++tn)
                    C[(size_t)row * Nc + bn + tn * 16 + mr] = acc[tm][tn][r];
            }
        }
    }
}

// ---------------- edge scatter: agg[dst] += h[src] * norm ----------------
__global__ __launch_bounds__(256) void scatter_edges(
    const float* __restrict__ h, float* __restrict__ agg,
    const int* __restrict__ src, const int* __restrict__ dst,
    const float* __restrict__ dis, int Df)
{
    int e = blockIdx.x;
    int s, d; float w;
    if (e < N_EDGES) {
        s = src[e]; d = dst[e];
        w = dis[s] * dis[d];
    } else {
        int i = e - N_EDGES;
        s = d = i;
        float di = dis[i];
        w = di * di;
    }
    const float* hp = h + (size_t)s * Df;
    float* ap = agg + (size_t)d * Df;
    for (int f = threadIdx.x; f < Df; f += blockDim.x)
        atomicAdd(ap + f, hp[f] * w);
}

__global__ void bias_relu(float* x, const float* __restrict__ bias, int Df, int do_relu) {
    int n = blockIdx.x;
    float* p = x + (size_t)n * Df;
    for (int f = threadIdx.x; f < Df; f += blockDim.x) {
        float v = p[f] + bias[f];
        p[f] = do_relu ? fmaxf(v, 0.0f) : v;
    }
}

// ---------------- mean pool over graphs ----------------
__global__ void pool_accum(const float* __restrict__ x, const int* __restrict__ batch,
                           float* pool, float* cnt) {
    int n = blockIdx.x;
    int g = batch[n];
    if (threadIdx.x == 0) atomicAdd(&cnt[g], 1.0f);
    for (int f = threadIdx.x; f < 320; f += blockDim.x)
        atomicAdd(&pool[g * 320 + f], x[(size_t)n * 320 + f]);
}
__global__ void pool_div(float* pool, const float* __restrict__ cnt) {
    int g = blockIdx.x;
    float c = fmaxf(cnt[g], 1.0f);
    for (int f = threadIdx.x; f < 320; f += blockDim.x)
        pool[g * 320 + f] /= c;
}

// ---------------- small MLP layers (M=64 rows) ----------------
__global__ void mlp_linear(const float* __restrict__ in, const float* __restrict__ W,
                           const float* __restrict__ b, float* __restrict__ out,
                           int M, int K, int Nc, int do_relu) {
    int idx = blockIdx.x * blockDim.x + threadIdx.x;
    if (idx >= M * Nc) return;
    int m = idx / Nc, c = idx % Nc;
    float s = b[c];
    const float* ip = in + (size_t)m * K;
    for (int k = 0; k < K; ++k) s += ip[k] * W[(size_t)k * Nc + c];
    out[idx] = do_relu ? fmaxf(s, 0.0f) : s;
}

__global__ void concat_k(const float* __restrict__ fp, const float* __restrict__ xt,
                         float* __restrict__ xc) {
    int idx = blockIdx.x * blockDim.x + threadIdx.x;
    if (idx >= NGRAPH * 193) return;
    int g = idx / 193, j = idx % 193;
    xc[idx] = (j < FPD) ? fp[g * FPD + j] : xt[g * 128 + (j - FPD)];
}

extern "C" void kernel_launch(void* const* d_in, const int* in_sizes, int n_in,
                              void* d_out, int out_size, void* d_ws, size_t ws_size,
                              hipStream_t stream) {
    const float* x    = (const float*)d_in[0];
    const int*   eidx = (const int*)d_in[1];
    const int*   batch= (const int*)d_in[2];
    const float* fp_x = (const float*)d_in[3];
    const float* W1 = (const float*)d_in[4];  const float* b1 = (const float*)d_in[5];
    const float* W2 = (const float*)d_in[6];  const float* b2 = (const float*)d_in[7];
    const float* W3 = (const float*)d_in[8];  const float* b3 = (const float*)d_in[9];
    const float* Wg1= (const float*)d_in[10]; const float* bg1= (const float*)d_in[11];
    const float* Wg2= (const float*)d_in[12]; const float* bg2= (const float*)d_in[13];
    const float* Wf1= (const float*)d_in[14]; const float* bf1= (const float*)d_in[15];
    const float* Wf2= (const float*)d_in[16]; const float* bf2= (const float*)d_in[17];
    const float* Wo = (const float*)d_in[18]; const float* bo = (const float*)d_in[19];
    float* out = (float*)d_out;

    const int* src = eidx;
    const int* dst = eidx + N_EDGES;

    // workspace layout (floats)
    float* ws  = (float*)d_ws;
    float* dis = ws;                                   // 20480
    float* h   = dis + 20480;                          // 25,600,000 f32 region
    float* agg = h + (size_t)N_NODES * 1280;           // 25,600,000 f32 region
    float* pool= agg + (size_t)N_NODES * 1280;         // 20480
    float* cnt = pool + NGRAPH * 320;                  // 64
    float* m1  = cnt + 64;                             // 64*1024
    float* m2  = m1 + NGRAPH * 1024;                   // 64*128
    float* xc  = m2 + NGRAPH * 128;                    // 64*193
    float* f1  = xc + NGRAPH * 193 + 3;                // 64*1024
    float* f2  = f1 + NGRAPH * 1024;                   // 64*512
    ushort* Wt = (ushort*)(f2 + NGRAPH * 512 + 64);    // up to 1280*1280 bf16

    // bf16 activation overlays (regions unused at GEMM time):
    ushort* Abf1 = (ushort*)agg;                       // 51.2MB in agg region (zeroed after GEMM)
    ushort* AbfH = (ushort*)(h + 12800000);            // upper half of h region

    // ---- degrees / symmetric norm ----
    init_deg<<<(N_NODES + 255) / 256, 256, 0, stream>>>(dis);
    count_deg<<<(N_EDGES + 255) / 256, 256, 0, stream>>>(dst, dis);
    deg_to_dis<<<(N_NODES + 255) / 256, 256, 0, stream>>>(dis);

    // ---- layer 1: h = x@W1 ; agg = S h ; relu(agg + b1) ----
    {
        long long ne = (long long)N_NODES * 1280;
        transpose_conv<<<dim3(1280 / 32, 1280 / 32), dim3(32, 8), 0, stream>>>(W1, Wt, 1280, 1280);
        conv_f32_bf16<<<(unsigned)((ne / 4 + 255) / 256), 256, 0, stream>>>(x, Abf1, ne);
        dim3 g((N_NODES + 255) / 256, 1280 / 64);
        gemm_bf16<<<g, 256, 0, stream>>>(Abf1, Wt, h, N_NODES, 1280, 1280);
        zero_f32<<<(unsigned)((ne + 255) / 256), 256, 0, stream>>>(agg, ne);
        scatter_edges<<<N_EDGES + N_NODES, 256, 0, stream>>>(h, agg, src, dst, dis, 1280);
        bias_relu<<<N_NODES, 256, 0, stream>>>(agg, b1, 1280, 1);
    }
    // ---- layer 2: h = agg@W2 (640) ----
    {
        long long ne_in = (long long)N_NODES * 1280;
        long long ne_out = (long long)N_NODES * 640;
        transpose_conv<<<dim3(1280 / 32, 640 / 32), dim3(32, 8), 0, stream>>>(W2, Wt, 1280, 640);
        conv_f32_bf16<<<(unsigned)((ne_in / 4 + 255) / 256), 256, 0, stream>>>(agg, AbfH, ne_in);
        dim3 g((N_NODES + 255) / 256, 640 / 64);
        gemm_bf16<<<g, 256, 0, stream>>>(AbfH, Wt, h, N_NODES, 1280, 640);
        zero_f32<<<(unsigned)((ne_out + 255) / 256), 256, 0, stream>>>(agg, ne_out);
        scatter_edges<<<N_EDGES + N_NODES, 256, 0, stream>>>(h, agg, src, dst, dis, 640);
        bias_relu<<<N_NODES, 256, 0, stream>>>(agg, b2, 640, 1);
    }
    // ---- layer 3: h = agg@W3 (320) ----
    {
        long long ne_in = (long long)N_NODES * 640;
        long long ne_out = (long long)N_NODES * 320;
        transpose_conv<<<dim3(640 / 32, 320 / 32), dim3(32, 8), 0, stream>>>(W3, Wt, 640, 320);
        conv_f32_bf16<<<(unsigned)((ne_in / 4 + 255) / 256), 256, 0, stream>>>(agg, AbfH, ne_in);
        dim3 g((N_NODES + 255) / 256, 320 / 64);
        gemm_bf16<<<g, 256, 0, stream>>>(AbfH, Wt, h, N_NODES, 640, 320);
        zero_f32<<<(unsigned)((ne_out + 255) / 256), 256, 0, stream>>>(agg, ne_out);
        scatter_edges<<<N_EDGES + N_NODES, 256, 0, stream>>>(h, agg, src, dst, dis, 320);
        bias_relu<<<N_NODES, 256, 0, stream>>>(agg, b3, 320, 1);
    }

    // ---- global mean pool ----
    {
        long long tot = NGRAPH * 320 + 64;
        zero_f32<<<(unsigned)((tot + 255) / 256), 256, 0, stream>>>(pool, tot);
        pool_accum<<<N_NODES, 256, 0, stream>>>(agg, batch, pool, cnt);
        pool_div<<<NGRAPH, 256, 0, stream>>>(pool, cnt);
    }

    // ---- MLP head ----
    mlp_linear<<<(NGRAPH * 1024 + 255) / 256, 256, 0, stream>>>(pool, Wg1, bg1, m1, NGRAPH, 320, 1024, 1);
    mlp_linear<<<(NGRAPH * 128 + 255) / 256, 256, 0, stream>>>(m1, Wg2, bg2, m2, NGRAPH, 1024, 128, 0);
    concat_k<<<(NGRAPH * 193 + 255) / 256, 256, 0, stream>>>(fp_x, m2, xc);
    mlp_linear<<<(NGRAPH * 1024 + 255) / 256, 256, 0, stream>>>(xc, Wf1, bf1, f1, NGRAPH, 193, 1024, 1);
    mlp_linear<<<(NGRAPH * 512 + 255) / 256, 256, 0, stream>>>(f1, Wf2, bf2, f2, NGRAPH, 1024, 512, 1);
    mlp_linear<<<1, 256, 0, stream>>>(f2, Wo, bo, out, NGRAPH, 512, 1, 0);
}

// Round 3
// 2191.839 us; speedup vs baseline: 2.4975x; 1.9144x over previous
//
#include <hip/hip_runtime.h>
#include <hip/hip_bf16.h>

#define N_NODES 20000
#define N_EDGES 320000
#define NGRAPH  64
#define FPD     65

typedef __attribute__((ext_vector_type(8))) __bf16 bf16x8;
typedef __attribute__((ext_vector_type(4))) float floatx4;

__device__ inline float bf2f(ushort u) {
    union { unsigned int i; float f; } c; c.i = ((unsigned int)u) << 16; return c.f;
}
__device__ inline ushort f2bf(float v) {
    __hip_bfloat16 h = __float2bfloat16(v);
    return *(ushort*)&h;
}

// ---------------- CSR build ----------------
__global__ void init_cnt(int* cnt) {
    int i = blockIdx.x * blockDim.x + threadIdx.x;
    if (i < N_NODES) cnt[i] = 1;   // self-loop
}
__global__ void count_in(const int* __restrict__ dst, int* cnt) {
    int e = blockIdx.x * blockDim.x + threadIdx.x;
    if (e < N_EDGES) atomicAdd(&cnt[dst[e]], 1);
}
__global__ void make_dis(const int* __restrict__ cnt, float* dis) {
    int i = blockIdx.x * blockDim.x + threadIdx.x;
    if (i < N_NODES) dis[i] = rsqrtf((float)cnt[i]);   // cnt >= 1 always
}
// one-block chunked exclusive scan: off[0..N], cursor = copy
__global__ __launch_bounds__(256) void scan_offsets(const int* __restrict__ cnt,
                                                    int* __restrict__ off, int* __restrict__ cursor) {
    __shared__ int part[256];
    int t = threadIdx.x;
    const int chunk = (N_NODES + 255) / 256;   // 79
    int lo = t * chunk, hi = min(lo + chunk, N_NODES);
    int s = 0;
    for (int i = lo; i < hi; ++i) s += cnt[i];
    part[t] = s;
    __syncthreads();
    for (int d = 1; d < 256; d <<= 1) {
        int v = (t >= d) ? part[t - d] : 0;
        __syncthreads();
        part[t] += v;
        __syncthreads();
    }
    int base = part[t] - s;   // exclusive
    for (int i = lo; i < hi; ++i) {
        off[i] = base; cursor[i] = base;
        base += cnt[i];
    }
    if (t == 255) off[N_NODES] = part[255];
}
__global__ void fill_csr(const int* __restrict__ src, const int* __restrict__ dst,
                         const float* __restrict__ dis, int* cursor,
                         int* __restrict__ esrc, float* __restrict__ ew) {
    int e = blockIdx.x * blockDim.x + threadIdx.x;
    if (e >= N_EDGES + N_NODES) return;
    int s, d; float w;
    if (e < N_EDGES) { s = src[e]; d = dst[e]; w = dis[s] * dis[d]; }
    else { s = d = e - N_EDGES; w = dis[s] * dis[s]; }
    int pos = atomicAdd(&cursor[d], 1);
    esrc[pos] = s; ew[pos] = w;
}

// ---------------- utility ----------------
__global__ void zero_f32(float* p, long long n) {
    long long i = (long long)blockIdx.x * blockDim.x + threadIdx.x;
    if (i < n) p[i] = 0.0f;
}
__global__ void conv_f32_bf16(const float* __restrict__ in, ushort* __restrict__ out, long long n) {
    long long i = ((long long)blockIdx.x * blockDim.x + threadIdx.x) * 4;
    if (i >= n) return;
    float4 v = *(const float4*)(in + i);
    ushort4 o;
    o.x = f2bf(v.x); o.y = f2bf(v.y); o.z = f2bf(v.z); o.w = f2bf(v.w);
    *(ushort4*)(out + i) = o;
}
// W[K][Nc] f32 -> Wt[Nc][K] bf16
__global__ void transpose_conv(const float* __restrict__ W, ushort* __restrict__ Wt, int K, int Nc) {
    __shared__ float t[32][33];
    int k0 = blockIdx.x * 32, n0 = blockIdx.y * 32;
    int tx = threadIdx.x, ty = threadIdx.y;
    #pragma unroll
    for (int i = 0; i < 4; ++i)
        t[ty + i * 8][tx] = W[(size_t)(k0 + ty + i * 8) * Nc + n0 + tx];
    __syncthreads();
    #pragma unroll
    for (int i = 0; i < 4; ++i)
        Wt[(size_t)(n0 + ty + i * 8) * K + k0 + tx] = f2bf(t[tx][ty + i * 8]);
}

// ---------------- bf16 MFMA GEMM: C[M,Nc](bf16) = A[M,K] @ Bt[Nc,K]^T ----------------
#define APAD 40
__global__ __launch_bounds__(256) void gemm_bf16(
    const ushort* __restrict__ A, const ushort* __restrict__ Bt,
    ushort* __restrict__ C, int M, int K, int Nc)
{
    __shared__ ushort As[256 * APAD];
    __shared__ ushort Bs[64 * APAD];
    const int tid = threadIdx.x;
    const int wid = tid >> 6, lane = tid & 63;
    const int quad = lane >> 4, mr = lane & 15;
    const int bm = blockIdx.x * 256, bn = blockIdx.y * 64;

    floatx4 acc[4][4];
    #pragma unroll
    for (int i = 0; i < 4; ++i)
        #pragma unroll
        for (int j = 0; j < 4; ++j)
            acc[i][j] = (floatx4){0.f, 0.f, 0.f, 0.f};

    for (int k0 = 0; k0 < K; k0 += 32) {
        #pragma unroll
        for (int it = 0; it < 4; ++it) {
            int idx = tid + it * 256;
            int row = idx >> 2, q = idx & 3;
            int gr = bm + row;
            int4 v = make_int4(0, 0, 0, 0);
            if (gr < M) v = *(const int4*)(A + (size_t)gr * K + k0 + q * 8);
            *(int4*)&As[row * APAD + q * 8] = v;
        }
        {
            int row = tid >> 2, q = tid & 3;
            int4 v = *(const int4*)(Bt + (size_t)(bn + row) * K + k0 + q * 8);
            *(int4*)&Bs[row * APAD + q * 8] = v;
        }
        __syncthreads();

        bf16x8 af[4], bfv[4];
        #pragma unroll
        for (int t = 0; t < 4; ++t)
            af[t] = *(const bf16x8*)&As[(wid * 64 + t * 16 + mr) * APAD + quad * 8];
        #pragma unroll
        for (int t = 0; t < 4; ++t)
            bfv[t] = *(const bf16x8*)&Bs[(t * 16 + mr) * APAD + quad * 8];

        #pragma unroll
        for (int tm = 0; tm < 4; ++tm)
            #pragma unroll
            for (int tn = 0; tn < 4; ++tn)
                acc[tm][tn] = __builtin_amdgcn_mfma_f32_16x16x32_bf16(af[tm], bfv[tn], acc[tm][tn], 0, 0, 0);
        __syncthreads();
    }

    // C/D layout: col = lane&15, row = quad*4 + reg
    #pragma unroll
    for (int tm = 0; tm < 4; ++tm) {
        int rowb = bm + wid * 64 + tm * 16 + quad * 4;
        #pragma unroll
        for (int r = 0; r < 4; ++r) {
            int row = rowb + r;
            if (row < M) {
                #pragma unroll
                for (int tn = 0; tn < 4; ++tn)
                    C[(size_t)row * Nc + bn + tn * 16 + mr] = f2bf(acc[tm][tn][r]);
            }
        }
    }
}

// ---------------- CSR gather + bias + relu ----------------
// out[n] = relu( sum_{e in in(n)} w_e * h[src_e] + b ). h is bf16 [N][Df].
#define GMAXI 3   // supports Df <= 1536
__global__ __launch_bounds__(256) void gather_csr(
    const ushort* __restrict__ h, const int* __restrict__ off,
    const int* __restrict__ esrc, const float* __restrict__ ew,
    const float* __restrict__ bias, ushort* __restrict__ out_bf,
    float* __restrict__ out_f32, int Df, int wbf, int wf32)
{
    int n = blockIdx.x;
    int tid = threadIdx.x;
    const int half = Df >> 1;
    float2 acc[GMAXI];
    #pragma unroll
    for (int i = 0; i < GMAXI; ++i) acc[i] = make_float2(0.f, 0.f);

    int e0 = off[n], e1 = off[n + 1];
    for (int e = e0; e < e1; ++e) {
        int s = esrc[e];
        float w = ew[e];
        const ushort* row = h + (size_t)s * Df;
        #pragma unroll
        for (int i = 0; i < GMAXI; ++i) {
            int f2 = tid + i * 256;
            if (f2 < half) {
                ushort2 hv = *(const ushort2*)(row + f2 * 2);
                acc[i].x += w * bf2f(hv.x);
                acc[i].y += w * bf2f(hv.y);
            }
        }
    }
    #pragma unroll
    for (int i = 0; i < GMAXI; ++i) {
        int f2 = tid + i * 256;
        if (f2 < half) {
            int f = f2 * 2;
            float vx = fmaxf(acc[i].x + bias[f], 0.f);
            float vy = fmaxf(acc[i].y + bias[f + 1], 0.f);
            if (wbf) {
                ushort2 o; o.x = f2bf(vx); o.y = f2bf(vy);
                *(ushort2*)(out_bf + (size_t)n * Df + f) = o;
            }
            if (wf32)
                *(float2*)(out_f32 + (size_t)n * Df + f) = make_float2(vx, vy);
        }
    }
}

// ---------------- mean pool over graphs ----------------
__global__ void pool_accum(const float* __restrict__ x, const int* __restrict__ batch,
                           float* pool, float* cnt) {
    int n = blockIdx.x;
    int g = batch[n];
    if (threadIdx.x == 0) atomicAdd(&cnt[g], 1.0f);
    for (int f = threadIdx.x; f < 320; f += blockDim.x)
        atomicAdd(&pool[g * 320 + f], x[(size_t)n * 320 + f]);
}
__global__ void pool_div(float* pool, const float* __restrict__ cnt) {
    int g = blockIdx.x;
    float c = fmaxf(cnt[g], 1.0f);
    for (int f = threadIdx.x; f < 320; f += blockDim.x)
        pool[g * 320 + f] /= c;
}

// ---------------- small MLP layers (M=64 rows) ----------------
__global__ void mlp_linear(const float* __restrict__ in, const float* __restrict__ W,
                           const float* __restrict__ b, float* __restrict__ out,
                           int M, int K, int Nc, int do_relu) {
    int idx = blockIdx.x * blockDim.x + threadIdx.x;
    if (idx >= M * Nc) return;
    int m = idx / Nc, c = idx % Nc;
    float s = b[c];
    const float* ip = in + (size_t)m * K;
    for (int k = 0; k < K; ++k) s += ip[k] * W[(size_t)k * Nc + c];
    out[idx] = do_relu ? fmaxf(s, 0.0f) : s;
}

__global__ void concat_k(const float* __restrict__ fp, const float* __restrict__ xt,
                         float* __restrict__ xc) {
    int idx = blockIdx.x * blockDim.x + threadIdx.x;
    if (idx >= NGRAPH * 193) return;
    int g = idx / 193, j = idx % 193;
    xc[idx] = (j < FPD) ? fp[g * FPD + j] : xt[g * 128 + (j - FPD)];
}

extern "C" void kernel_launch(void* const* d_in, const int* in_sizes, int n_in,
                              void* d_out, int out_size, void* d_ws, size_t ws_size,
                              hipStream_t stream) {
    const float* x    = (const float*)d_in[0];
    const int*   eidx = (const int*)d_in[1];
    const int*   batch= (const int*)d_in[2];
    const float* fp_x = (const float*)d_in[3];
    const float* W1 = (const float*)d_in[4];  const float* b1 = (const float*)d_in[5];
    const float* W2 = (const float*)d_in[6];  const float* b2 = (const float*)d_in[7];
    const float* W3 = (const float*)d_in[8];  const float* b3 = (const float*)d_in[9];
    const float* Wg1= (const float*)d_in[10]; const float* bg1= (const float*)d_in[11];
    const float* Wg2= (const float*)d_in[12]; const float* bg2= (const float*)d_in[13];
    const float* Wf1= (const float*)d_in[14]; const float* bf1= (const float*)d_in[15];
    const float* Wf2= (const float*)d_in[16]; const float* bf2= (const float*)d_in[17];
    const float* Wo = (const float*)d_in[18]; const float* bo = (const float*)d_in[19];
    float* out = (float*)d_out;

    const int* src = eidx;
    const int* dst = eidx + N_EDGES;

    // ---- workspace layout (bytes, 16B-aligned blocks) ----
    char* p = (char*)d_ws;
    float* dis   = (float*)p;  p += 20480 * 4;
    int*   cntI  = (int*)p;    p += 20480 * 4;
    int*   off   = (int*)p;    p += 20480 * 4;      // needs 20001
    int*   cursor= (int*)p;    p += 20480 * 4;
    int*   esrc  = (int*)p;    p += 340992 * 4;
    float* ew    = (float*)p;  p += 340992 * 4;
    ushort* xbf  = (ushort*)p; p += (size_t)N_NODES * 1280 * 2;   // layer-1 input bf16
    ushort* hbf  = (ushort*)p; p += (size_t)N_NODES * 1280 * 2;   // GEMM output bf16
    ushort* abf  = (ushort*)p; p += (size_t)N_NODES * 1280 * 2;   // gather output bf16
    float* a3f   = (float*)p;  p += (size_t)N_NODES * 320 * 4;    // layer-3 output fp32
    ushort* Wt   = (ushort*)p; p += (size_t)1280 * 1280 * 2;
    float* pool  = (float*)p;  p += NGRAPH * 320 * 4;
    float* cntf  = (float*)p;  p += 256 * 4;
    float* m1    = (float*)p;  p += NGRAPH * 1024 * 4;
    float* m2    = (float*)p;  p += NGRAPH * 128 * 4;
    float* xc    = (float*)p;  p += (NGRAPH * 193 + 16) * 4;
    float* f1    = (float*)p;  p += NGRAPH * 1024 * 4;
    float* f2    = (float*)p;  p += NGRAPH * 512 * 4;

    // ---- CSR build (shared by all 3 layers) ----
    init_cnt<<<(N_NODES + 255) / 256, 256, 0, stream>>>(cntI);
    count_in<<<(N_EDGES + 255) / 256, 256, 0, stream>>>(dst, cntI);
    make_dis<<<(N_NODES + 255) / 256, 256, 0, stream>>>(cntI, dis);
    scan_offsets<<<1, 256, 0, stream>>>(cntI, off, cursor);
    fill_csr<<<(N_EDGES + N_NODES + 255) / 256, 256, 0, stream>>>(src, dst, dis, cursor, esrc, ew);

    // ---- layer 1 ----
    {
        long long ne = (long long)N_NODES * 1280;
        conv_f32_bf16<<<(unsigned)((ne / 4 + 255) / 256), 256, 0, stream>>>(x, xbf, ne);
        transpose_conv<<<dim3(1280 / 32, 1280 / 32), dim3(32, 8), 0, stream>>>(W1, Wt, 1280, 1280);
        dim3 g((N_NODES + 255) / 256, 1280 / 64);
        gemm_bf16<<<g, 256, 0, stream>>>(xbf, Wt, hbf, N_NODES, 1280, 1280);
        gather_csr<<<N_NODES, 256, 0, stream>>>(hbf, off, esrc, ew, b1, abf, (float*)nullptr, 1280, 1, 0);
    }
    // ---- layer 2 ----
    {
        transpose_conv<<<dim3(1280 / 32, 640 / 32), dim3(32, 8), 0, stream>>>(W2, Wt, 1280, 640);
        dim3 g((N_NODES + 255) / 256, 640 / 64);
        gemm_bf16<<<g, 256, 0, stream>>>(abf, Wt, hbf, N_NODES, 1280, 640);
        gather_csr<<<N_NODES, 256, 0, stream>>>(hbf, off, esrc, ew, b2, abf, (float*)nullptr, 640, 1, 0);
    }
    // ---- layer 3 ----
    {
        transpose_conv<<<dim3(640 / 32, 320 / 32), dim3(32, 8), 0, stream>>>(W3, Wt, 640, 320);
        dim3 g((N_NODES + 255) / 256, 320 / 64);
        gemm_bf16<<<g, 256, 0, stream>>>(abf, Wt, hbf, N_NODES, 640, 320);
        gather_csr<<<N_NODES, 256, 0, stream>>>(hbf, off, esrc, ew, b3, (ushort*)nullptr, a3f, 320, 0, 1);
    }

    // ---- global mean pool ----
    {
        long long tot = NGRAPH * 320 + 256;   // pool + cntf contiguous
        zero_f32<<<(unsigned)((tot + 255) / 256), 256, 0, stream>>>(pool, tot);
        pool_accum<<<N_NODES, 256, 0, stream>>>(a3f, batch, pool, cntf);
        pool_div<<<NGRAPH, 256, 0, stream>>>(pool, cntf);
    }

    // ---- MLP head ----
    mlp_linear<<<(NGRAPH * 1024 + 255) / 256, 256, 0, stream>>>(pool, Wg1, bg1, m1, NGRAPH, 320, 1024, 1);
    mlp_linear<<<(NGRAPH * 128 + 255) / 256, 256, 0, stream>>>(m1, Wg2, bg2, m2, NGRAPH, 1024, 128, 0);
    concat_k<<<(NGRAPH * 193 + 255) / 256, 256, 0, stream>>>(fp_x, m2, xc);
    mlp_linear<<<(NGRAPH * 1024 + 255) / 256, 256, 0, stream>>>(xc, Wf1, bf1, f1, NGRAPH, 193, 1024, 1);
    mlp_linear<<<(NGRAPH * 512 + 255) / 256, 256, 0, stream>>>(f1, Wf2, bf2, f2, NGRAPH, 1024, 512, 1);
    mlp_linear<<<1, 256, 0, stream>>>(f2, Wo, bo, out, NGRAPH, 512, 1, 0);
}

// Round 4
// 1479.913 us; speedup vs baseline: 3.6989x; 1.4811x over previous
//
#include <hip/hip_runtime.h>
#include <hip/hip_bf16.h>

#define N_NODES 20000
#define N_EDGES 320000
#define NGRAPH  64
#define FPD     65

typedef __attribute__((ext_vector_type(8))) __bf16 bf16x8;
typedef __attribute__((ext_vector_type(4))) float floatx4;

__device__ inline float bf2f(ushort u) {
    union { unsigned int i; float f; } c; c.i = ((unsigned int)u) << 16; return c.f;
}
__device__ inline ushort f2bf(float v) {
    __hip_bfloat16 h = __float2bfloat16(v);
    return *(ushort*)&h;
}

// ---------------- CSR build ----------------
__global__ void init_cnt(int* cnt) {
    int i = blockIdx.x * blockDim.x + threadIdx.x;
    if (i < N_NODES) cnt[i] = 1;   // self-loop
}
__global__ void count_in(const int* __restrict__ dst, int* cnt) {
    int e = blockIdx.x * blockDim.x + threadIdx.x;
    if (e < N_EDGES) atomicAdd(&cnt[dst[e]], 1);
}
__global__ void make_dis(const int* __restrict__ cnt, float* dis) {
    int i = blockIdx.x * blockDim.x + threadIdx.x;
    if (i < N_NODES) dis[i] = rsqrtf((float)cnt[i]);   // cnt >= 1 always
}
// one-block chunked exclusive scan: off[0..N], cursor = copy
__global__ __launch_bounds__(256) void scan_offsets(const int* __restrict__ cnt,
                                                    int* __restrict__ off, int* __restrict__ cursor) {
    __shared__ int part[256];
    int t = threadIdx.x;
    const int chunk = (N_NODES + 255) / 256;   // 79
    int lo = t * chunk, hi = min(lo + chunk, N_NODES);
    int s = 0;
    for (int i = lo; i < hi; ++i) s += cnt[i];
    part[t] = s;
    __syncthreads();
    for (int d = 1; d < 256; d <<= 1) {
        int v = (t >= d) ? part[t - d] : 0;
        __syncthreads();
        part[t] += v;
        __syncthreads();
    }
    int base = part[t] - s;   // exclusive
    for (int i = lo; i < hi; ++i) {
        off[i] = base; cursor[i] = base;
        base += cnt[i];
    }
    if (t == 255) off[N_NODES] = part[255];
}
__global__ void fill_csr(const int* __restrict__ src, const int* __restrict__ dst,
                         const float* __restrict__ dis, int* cursor,
                         int* __restrict__ esrc, float* __restrict__ ew) {
    int e = blockIdx.x * blockDim.x + threadIdx.x;
    if (e >= N_EDGES + N_NODES) return;
    int s, d; float w;
    if (e < N_EDGES) { s = src[e]; d = dst[e]; w = dis[s] * dis[d]; }
    else { s = d = e - N_EDGES; w = dis[s] * dis[s]; }
    int pos = atomicAdd(&cursor[d], 1);
    esrc[pos] = s; ew[pos] = w;
}

// ---------------- utility ----------------
__global__ void zero_f32(float* p, long long n) {
    long long i = (long long)blockIdx.x * blockDim.x + threadIdx.x;
    if (i < n) p[i] = 0.0f;
}
__global__ void conv_f32_bf16(const float* __restrict__ in, ushort* __restrict__ out, long long n) {
    long long i = ((long long)blockIdx.x * blockDim.x + threadIdx.x) * 4;
    if (i >= n) return;
    float4 v = *(const float4*)(in + i);
    ushort4 o;
    o.x = f2bf(v.x); o.y = f2bf(v.y); o.z = f2bf(v.z); o.w = f2bf(v.w);
    *(ushort4*)(out + i) = o;
}
// W[K][Nc] f32 -> Wt[Nc][K] bf16
__global__ void transpose_conv(const float* __restrict__ W, ushort* __restrict__ Wt, int K, int Nc) {
    __shared__ float t[32][33];
    int k0 = blockIdx.x * 32, n0 = blockIdx.y * 32;
    int tx = threadIdx.x, ty = threadIdx.y;
    #pragma unroll
    for (int i = 0; i < 4; ++i)
        t[ty + i * 8][tx] = W[(size_t)(k0 + ty + i * 8) * Nc + n0 + tx];
    __syncthreads();
    #pragma unroll
    for (int i = 0; i < 4; ++i)
        Wt[(size_t)(n0 + ty + i * 8) * K + k0 + tx] = f2bf(t[tx][ty + i * 8]);
}

// ---------------- bf16 MFMA GEMM: C[M,Nc](bf16) = A[M,K] @ Bt[Nc,K]^T ----------------
#define APAD 40
__global__ __launch_bounds__(256) void gemm_bf16(
    const ushort* __restrict__ A, const ushort* __restrict__ Bt,
    ushort* __restrict__ C, int M, int K, int Nc)
{
    __shared__ ushort As[256 * APAD];
    __shared__ ushort Bs[64 * APAD];
    const int tid = threadIdx.x;
    const int wid = tid >> 6, lane = tid & 63;
    const int quad = lane >> 4, mr = lane & 15;
    const int bm = blockIdx.x * 256, bn = blockIdx.y * 64;

    floatx4 acc[4][4];
    #pragma unroll
    for (int i = 0; i < 4; ++i)
        #pragma unroll
        for (int j = 0; j < 4; ++j)
            acc[i][j] = (floatx4){0.f, 0.f, 0.f, 0.f};

    for (int k0 = 0; k0 < K; k0 += 32) {
        #pragma unroll
        for (int it = 0; it < 4; ++it) {
            int idx = tid + it * 256;
            int row = idx >> 2, q = idx & 3;
            int gr = bm + row;
            int4 v = make_int4(0, 0, 0, 0);
            if (gr < M) v = *(const int4*)(A + (size_t)gr * K + k0 + q * 8);
            *(int4*)&As[row * APAD + q * 8] = v;
        }
        {
            int row = tid >> 2, q = tid & 3;
            int4 v = *(const int4*)(Bt + (size_t)(bn + row) * K + k0 + q * 8);
            *(int4*)&Bs[row * APAD + q * 8] = v;
        }
        __syncthreads();

        bf16x8 af[4], bfv[4];
        #pragma unroll
        for (int t = 0; t < 4; ++t)
            af[t] = *(const bf16x8*)&As[(wid * 64 + t * 16 + mr) * APAD + quad * 8];
        #pragma unroll
        for (int t = 0; t < 4; ++t)
            bfv[t] = *(const bf16x8*)&Bs[(t * 16 + mr) * APAD + quad * 8];

        #pragma unroll
        for (int tm = 0; tm < 4; ++tm)
            #pragma unroll
            for (int tn = 0; tn < 4; ++tn)
                acc[tm][tn] = __builtin_amdgcn_mfma_f32_16x16x32_bf16(af[tm], bfv[tn], acc[tm][tn], 0, 0, 0);
        __syncthreads();
    }

    // C/D layout: col = lane&15, row = quad*4 + reg
    #pragma unroll
    for (int tm = 0; tm < 4; ++tm) {
        int rowb = bm + wid * 64 + tm * 16 + quad * 4;
        #pragma unroll
        for (int r = 0; r < 4; ++r) {
            int row = rowb + r;
            if (row < M) {
                #pragma unroll
                for (int tn = 0; tn < 4; ++tn)
                    C[(size_t)row * Nc + bn + tn * 16 + mr] = f2bf(acc[tm][tn][r]);
            }
        }
    }
}

// ---------------- CSR gather + bias + relu ----------------
#define GMAXI 3   // supports Df <= 1536
__global__ __launch_bounds__(256) void gather_csr(
    const ushort* __restrict__ h, const int* __restrict__ off,
    const int* __restrict__ esrc, const float* __restrict__ ew,
    const float* __restrict__ bias, ushort* __restrict__ out_bf,
    float* __restrict__ out_f32, int Df, int wbf, int wf32)
{
    int n = blockIdx.x;
    int tid = threadIdx.x;
    const int half = Df >> 1;
    float2 acc[GMAXI];
    #pragma unroll
    for (int i = 0; i < GMAXI; ++i) acc[i] = make_float2(0.f, 0.f);

    int e0 = off[n], e1 = off[n + 1];
    for (int e = e0; e < e1; ++e) {
        int s = esrc[e];
        float w = ew[e];
        const ushort* row = h + (size_t)s * Df;
        #pragma unroll
        for (int i = 0; i < GMAXI; ++i) {
            int f2 = tid + i * 256;
            if (f2 < half) {
                ushort2 hv = *(const ushort2*)(row + f2 * 2);
                acc[i].x += w * bf2f(hv.x);
                acc[i].y += w * bf2f(hv.y);
            }
        }
    }
    #pragma unroll
    for (int i = 0; i < GMAXI; ++i) {
        int f2 = tid + i * 256;
        if (f2 < half) {
            int f = f2 * 2;
            float vx = fmaxf(acc[i].x + bias[f], 0.f);
            float vy = fmaxf(acc[i].y + bias[f + 1], 0.f);
            if (wbf) {
                ushort2 o; o.x = f2bf(vx); o.y = f2bf(vy);
                *(ushort2*)(out_bf + (size_t)n * Df + f) = o;
            }
            if (wf32)
                *(float2*)(out_f32 + (size_t)n * Df + f) = make_float2(vx, vy);
        }
    }
}

// ---------------- mean pool over graphs ----------------
__global__ void pool_accum(const float* __restrict__ x, const int* __restrict__ batch,
                           float* pool, float* cnt) {
    int n = blockIdx.x;
    int g = batch[n];
    if (threadIdx.x == 0) atomicAdd(&cnt[g], 1.0f);
    for (int f = threadIdx.x; f < 320; f += blockDim.x)
        atomicAdd(&pool[g * 320 + f], x[(size_t)n * 320 + f]);
}
__global__ void pool_div(float* pool, const float* __restrict__ cnt) {
    int g = blockIdx.x;
    float c = fmaxf(cnt[g], 1.0f);
    for (int f = threadIdx.x; f < 320; f += blockDim.x)
        pool[g * 320 + f] /= c;
}

// ---------------- MLP head: templated compile-time-K GEMM ----------------
// thread-per-output, float4 in-loads (wave-uniform), 4 independent accumulators,
// full unroll -> deep load pipeline. K % 4 == 0 required (pad inputs).
template<int K, int RELU>
__global__ __launch_bounds__(256) void head_gemm(
    const float* __restrict__ in, int istride,
    const float* __restrict__ W, const float* __restrict__ b,
    float* __restrict__ out, int M, int Nc)
{
    int idx = blockIdx.x * blockDim.x + threadIdx.x;
    if (idx >= M * Nc) return;
    int m = idx / Nc, c = idx % Nc;
    const float* ip = in + (size_t)m * istride;
    const float* wp = W + c;
    float a0 = 0.f, a1 = 0.f, a2 = 0.f, a3 = 0.f;
    #pragma unroll
    for (int k = 0; k < K; k += 4) {
        float4 v = *(const float4*)(ip + k);
        a0 += v.x * wp[(size_t)(k + 0) * Nc];
        a1 += v.y * wp[(size_t)(k + 1) * Nc];
        a2 += v.z * wp[(size_t)(k + 2) * Nc];
        a3 += v.w * wp[(size_t)(k + 3) * Nc];
    }
    float s = (a0 + a1) + (a2 + a3) + b[c];
    out[idx] = RELU ? fmaxf(s, 0.f) : s;
}

// concat [fp_x | m2] into stride-208 rows, zero-padded
__global__ void concat_pad(const float* __restrict__ fp, const float* __restrict__ xt,
                           float* __restrict__ xc) {
    int idx = blockIdx.x * blockDim.x + threadIdx.x;
    if (idx >= NGRAPH * 208) return;
    int g = idx / 208, j = idx % 208;
    float v = 0.f;
    if (j < FPD) v = fp[g * FPD + j];
    else if (j < 193) v = xt[g * 128 + (j - FPD)];
    xc[idx] = v;
}
// pad Wf1[193][1024] -> Wp[208][1024] (zeros beyond row 192)
__global__ void pad_w(const float* __restrict__ Wf1, float* __restrict__ Wp) {
    int idx = blockIdx.x * blockDim.x + threadIdx.x;
    if (idx >= 208 * 1024) return;
    int k = idx / 1024;
    Wp[idx] = (k < 193) ? Wf1[idx] : 0.f;
}

// final dot: out[m] = f2[m,:512] . Wo + bo   (block per graph, shuffle+LDS reduce)
__global__ __launch_bounds__(256) void head_out(
    const float* __restrict__ f2, const float* __restrict__ Wo,
    const float* __restrict__ bo, float* __restrict__ out)
{
    int m = blockIdx.x;
    int t = threadIdx.x;
    float2 v = *(const float2*)(f2 + (size_t)m * 512 + t * 2);
    float2 w = *(const float2*)(Wo + t * 2);
    float s = v.x * w.x + v.y * w.y;
    #pragma unroll
    for (int o = 32; o > 0; o >>= 1) s += __shfl_down(s, o, 64);
    __shared__ float ps[4];
    if ((t & 63) == 0) ps[t >> 6] = s;
    __syncthreads();
    if (t == 0) out[m] = ps[0] + ps[1] + ps[2] + ps[3] + bo[0];
}

extern "C" void kernel_launch(void* const* d_in, const int* in_sizes, int n_in,
                              void* d_out, int out_size, void* d_ws, size_t ws_size,
                              hipStream_t stream) {
    const float* x    = (const float*)d_in[0];
    const int*   eidx = (const int*)d_in[1];
    const int*   batch= (const int*)d_in[2];
    const float* fp_x = (const float*)d_in[3];
    const float* W1 = (const float*)d_in[4];  const float* b1 = (const float*)d_in[5];
    const float* W2 = (const float*)d_in[6];  const float* b2 = (const float*)d_in[7];
    const float* W3 = (const float*)d_in[8];  const float* b3 = (const float*)d_in[9];
    const float* Wg1= (const float*)d_in[10]; const float* bg1= (const float*)d_in[11];
    const float* Wg2= (const float*)d_in[12]; const float* bg2= (const float*)d_in[13];
    const float* Wf1= (const float*)d_in[14]; const float* bf1= (const float*)d_in[15];
    const float* Wf2= (const float*)d_in[16]; const float* bf2= (const float*)d_in[17];
    const float* Wo = (const float*)d_in[18]; const float* bo = (const float*)d_in[19];
    float* out = (float*)d_out;

    const int* src = eidx;
    const int* dst = eidx + N_EDGES;

    // ---- workspace layout ----
    char* p = (char*)d_ws;
    float* dis   = (float*)p;  p += 20480 * 4;
    int*   cntI  = (int*)p;    p += 20480 * 4;
    int*   off   = (int*)p;    p += 20480 * 4;
    int*   cursor= (int*)p;    p += 20480 * 4;
    int*   esrc  = (int*)p;    p += 340992 * 4;
    float* ew    = (float*)p;  p += 340992 * 4;
    ushort* xbf  = (ushort*)p; p += (size_t)N_NODES * 1280 * 2;
    ushort* hbf  = (ushort*)p; p += (size_t)N_NODES * 1280 * 2;
    ushort* abf  = (ushort*)p; p += (size_t)N_NODES * 1280 * 2;
    float* a3f   = (float*)p;  p += (size_t)N_NODES * 320 * 4;
    ushort* Wt   = (ushort*)p; p += (size_t)1280 * 1280 * 2;
    float* pool  = (float*)p;  p += NGRAPH * 320 * 4;
    float* cntf  = (float*)p;  p += 256 * 4;
    float* m1    = (float*)p;  p += NGRAPH * 1024 * 4;
    float* m2    = (float*)p;  p += NGRAPH * 128 * 4;
    float* xc    = (float*)p;  p += NGRAPH * 208 * 4;
    float* f1    = (float*)p;  p += NGRAPH * 1024 * 4;
    float* f2    = (float*)p;  p += NGRAPH * 512 * 4;
    float* Wf1p  = (float*)p;  p += 208 * 1024 * 4;

    // ---- CSR build ----
    init_cnt<<<(N_NODES + 255) / 256, 256, 0, stream>>>(cntI);
    count_in<<<(N_EDGES + 255) / 256, 256, 0, stream>>>(dst, cntI);
    make_dis<<<(N_NODES + 255) / 256, 256, 0, stream>>>(cntI, dis);
    scan_offsets<<<1, 256, 0, stream>>>(cntI, off, cursor);
    fill_csr<<<(N_EDGES + N_NODES + 255) / 256, 256, 0, stream>>>(src, dst, dis, cursor, esrc, ew);

    // ---- layer 1 ----
    {
        long long ne = (long long)N_NODES * 1280;
        conv_f32_bf16<<<(unsigned)((ne / 4 + 255) / 256), 256, 0, stream>>>(x, xbf, ne);
        transpose_conv<<<dim3(1280 / 32, 1280 / 32), dim3(32, 8), 0, stream>>>(W1, Wt, 1280, 1280);
        dim3 g((N_NODES + 255) / 256, 1280 / 64);
        gemm_bf16<<<g, 256, 0, stream>>>(xbf, Wt, hbf, N_NODES, 1280, 1280);
        gather_csr<<<N_NODES, 256, 0, stream>>>(hbf, off, esrc, ew, b1, abf, (float*)nullptr, 1280, 1, 0);
    }
    // ---- layer 2 ----
    {
        transpose_conv<<<dim3(1280 / 32, 640 / 32), dim3(32, 8), 0, stream>>>(W2, Wt, 1280, 640);
        dim3 g((N_NODES + 255) / 256, 640 / 64);
        gemm_bf16<<<g, 256, 0, stream>>>(abf, Wt, hbf, N_NODES, 1280, 640);
        gather_csr<<<N_NODES, 256, 0, stream>>>(hbf, off, esrc, ew, b2, abf, (float*)nullptr, 640, 1, 0);
    }
    // ---- layer 3 ----
    {
        transpose_conv<<<dim3(640 / 32, 320 / 32), dim3(32, 8), 0, stream>>>(W3, Wt, 640, 320);
        dim3 g((N_NODES + 255) / 256, 320 / 64);
        gemm_bf16<<<g, 256, 0, stream>>>(abf, Wt, hbf, N_NODES, 640, 320);
        gather_csr<<<N_NODES, 256, 0, stream>>>(hbf, off, esrc, ew, b3, (ushort*)nullptr, a3f, 320, 0, 1);
    }

    // ---- global mean pool ----
    {
        long long tot = NGRAPH * 320 + 256;
        zero_f32<<<(unsigned)((tot + 255) / 256), 256, 0, stream>>>(pool, tot);
        pool_accum<<<N_NODES, 256, 0, stream>>>(a3f, batch, pool, cntf);
        pool_div<<<NGRAPH, 256, 0, stream>>>(pool, cntf);
    }

    // ---- MLP head ----
    head_gemm<320, 1><<<(NGRAPH * 1024 + 255) / 256, 256, 0, stream>>>(pool, 320, Wg1, bg1, m1, NGRAPH, 1024);
    head_gemm<1024, 0><<<(NGRAPH * 128 + 255) / 256, 256, 0, stream>>>(m1, 1024, Wg2, bg2, m2, NGRAPH, 128);
    concat_pad<<<(NGRAPH * 208 + 255) / 256, 256, 0, stream>>>(fp_x, m2, xc);
    pad_w<<<(208 * 1024 + 255) / 256, 256, 0, stream>>>(Wf1, Wf1p);
    head_gemm<208, 1><<<(NGRAPH * 1024 + 255) / 256, 256, 0, stream>>>(xc, 208, Wf1p, bf1, f1, NGRAPH, 1024);
    head_gemm<1024, 1><<<(NGRAPH * 512 + 255) / 256, 256, 0, stream>>>(f1, 1024, Wf2, bf2, f2, NGRAPH, 512);
    head_out<<<NGRAPH, 256, 0, stream>>>(f2, Wo, bo, out);
}

// Round 5
// 1358.184 us; speedup vs baseline: 4.0305x; 1.0896x over previous
//
#include <hip/hip_runtime.h>
#include <hip/hip_bf16.h>

#define N_NODES 20000
#define N_EDGES 320000
#define NGRAPH  64
#define FPD     65

typedef __attribute__((ext_vector_type(8))) __bf16 bf16x8;
typedef __attribute__((ext_vector_type(4))) float floatx4;

__device__ inline float bf2f(ushort u) {
    union { unsigned int i; float f; } c; c.i = ((unsigned int)u) << 16; return c.f;
}
__device__ inline ushort f2bf(float v) {
    __hip_bfloat16 h = __float2bfloat16(v);
    return *(ushort*)&h;
}
// async global->LDS, 16 B per lane; LDS dest must be wave-uniform-base + lane*16
__device__ __forceinline__ void gld_lds16(const ushort* g, ushort* l) {
    __builtin_amdgcn_global_load_lds(
        (const __attribute__((address_space(1))) unsigned int*)g,
        (__attribute__((address_space(3))) unsigned int*)l,
        16, 0, 0);
}

// ---------------- CSR build ----------------
__global__ void init_cnt(int* cnt) {
    int i = blockIdx.x * blockDim.x + threadIdx.x;
    if (i < N_NODES) cnt[i] = 1;   // self-loop
}
__global__ void count_in(const int* __restrict__ dst, int* cnt) {
    int e = blockIdx.x * blockDim.x + threadIdx.x;
    if (e < N_EDGES) atomicAdd(&cnt[dst[e]], 1);
}
__global__ void make_dis(const int* __restrict__ cnt, float* dis) {
    int i = blockIdx.x * blockDim.x + threadIdx.x;
    if (i < N_NODES) dis[i] = rsqrtf((float)cnt[i]);
}
__global__ __launch_bounds__(256) void scan_offsets(const int* __restrict__ cnt,
                                                    int* __restrict__ off, int* __restrict__ cursor) {
    __shared__ int part[256];
    int t = threadIdx.x;
    const int chunk = (N_NODES + 255) / 256;
    int lo = t * chunk, hi = min(lo + chunk, N_NODES);
    int s = 0;
    for (int i = lo; i < hi; ++i) s += cnt[i];
    part[t] = s;
    __syncthreads();
    for (int d = 1; d < 256; d <<= 1) {
        int v = (t >= d) ? part[t - d] : 0;
        __syncthreads();
        part[t] += v;
        __syncthreads();
    }
    int base = part[t] - s;
    for (int i = lo; i < hi; ++i) {
        off[i] = base; cursor[i] = base;
        base += cnt[i];
    }
    if (t == 255) off[N_NODES] = part[255];
}
__global__ void fill_csr(const int* __restrict__ src, const int* __restrict__ dst,
                         const float* __restrict__ dis, int* cursor,
                         int* __restrict__ esrc, float* __restrict__ ew) {
    int e = blockIdx.x * blockDim.x + threadIdx.x;
    if (e >= N_EDGES + N_NODES) return;
    int s, d; float w;
    if (e < N_EDGES) { s = src[e]; d = dst[e]; w = dis[s] * dis[d]; }
    else { s = d = e - N_EDGES; w = dis[s] * dis[s]; }
    int pos = atomicAdd(&cursor[d], 1);
    esrc[pos] = s; ew[pos] = w;
}

// ---------------- utility ----------------
__global__ void zero_f32(float* p, long long n) {
    long long i = (long long)blockIdx.x * blockDim.x + threadIdx.x;
    if (i < n) p[i] = 0.0f;
}
__global__ void conv_f32_bf16(const float* __restrict__ in, ushort* __restrict__ out, long long n) {
    long long i = ((long long)blockIdx.x * blockDim.x + threadIdx.x) * 4;
    if (i >= n) return;
    float4 v = *(const float4*)(in + i);
    ushort4 o;
    o.x = f2bf(v.x); o.y = f2bf(v.y); o.z = f2bf(v.z); o.w = f2bf(v.w);
    *(ushort4*)(out + i) = o;
}
// W[K][Nc] f32 -> Wt[Nc][K] bf16
__global__ void transpose_conv(const float* __restrict__ W, ushort* __restrict__ Wt, int K, int Nc) {
    __shared__ float t[32][33];
    int k0 = blockIdx.x * 32, n0 = blockIdx.y * 32;
    int tx = threadIdx.x, ty = threadIdx.y;
    #pragma unroll
    for (int i = 0; i < 4; ++i)
        t[ty + i * 8][tx] = W[(size_t)(k0 + ty + i * 8) * Nc + n0 + tx];
    __syncthreads();
    #pragma unroll
    for (int i = 0; i < 4; ++i)
        Wt[(size_t)(n0 + ty + i * 8) * K + k0 + tx] = f2bf(t[tx][ty + i * 8]);
}

// ---------------- bf16 MFMA GEMM: C[M,Nc](bf16) = A[M,K] @ Bt[Nc,K]^T ----------------
// Tile 256(M) x 64(N) x 32(K). grid.x = n-tiles (fast-varying -> A-panel L2 reuse),
// grid.y = m-tiles. Staging via global_load_lds width=16 (async DMA, no VGPR roundtrip).
// LDS unpadded (DMA requires lane-contiguous dest); b128 phase cost is inherent.
// OOB m-rows load in-workspace garbage; store guard drops them.
__global__ __launch_bounds__(256) void gemm_bf16(
    const ushort* __restrict__ A, const ushort* __restrict__ Bt,
    ushort* __restrict__ C, int M, int K, int Nc)
{
    __shared__ ushort As[256 * 32];   // 16 KB: row-major, row stride 32 bf16
    __shared__ ushort Bs[64 * 32];    // 4 KB
    const int tid = threadIdx.x;
    const int wid = tid >> 6, lane = tid & 63;
    const int quad = lane >> 4, mr = lane & 15;
    const int bn = blockIdx.x * 64, bm = blockIdx.y * 256;

    floatx4 acc[4][4];
    #pragma unroll
    for (int i = 0; i < 4; ++i)
        #pragma unroll
        for (int j = 0; j < 4; ++j)
            acc[i][j] = (floatx4){0.f, 0.f, 0.f, 0.f};

    // chunk c of A tile: row = c>>2, q = c&3  ->  LDS ushort offset c*8 (= row*32 + q*8)
    // A: 1024 chunks = 4 issues/thread; B: 256 chunks = 1 issue/thread.
    const int ca0 = tid;              // + i*256
    const int cb  = tid;

    for (int k0 = 0; k0 < K; k0 += 32) {
        #pragma unroll
        for (int i = 0; i < 4; ++i) {
            int c = ca0 + i * 256;
            int row = c >> 2, q = c & 3;
            gld_lds16(A + (size_t)(bm + row) * K + k0 + q * 8, &As[c * 8]);
        }
        {
            int row = cb >> 2, q = cb & 3;
            gld_lds16(Bt + (size_t)(bn + row) * K + k0 + q * 8, &Bs[cb * 8]);
        }
        __syncthreads();   // compiler emits s_waitcnt vmcnt(0) before s_barrier

        bf16x8 af[4], bfv[4];
        #pragma unroll
        for (int t = 0; t < 4; ++t)
            af[t] = *(const bf16x8*)&As[(wid * 64 + t * 16 + mr) * 32 + quad * 8];
        #pragma unroll
        for (int t = 0; t < 4; ++t)
            bfv[t] = *(const bf16x8*)&Bs[(t * 16 + mr) * 32 + quad * 8];

        #pragma unroll
        for (int tm = 0; tm < 4; ++tm)
            #pragma unroll
            for (int tn = 0; tn < 4; ++tn)
                acc[tm][tn] = __builtin_amdgcn_mfma_f32_16x16x32_bf16(af[tm], bfv[tn], acc[tm][tn], 0, 0, 0);
        __syncthreads();
    }

    // C/D layout: col = lane&15, row = quad*4 + reg
    #pragma unroll
    for (int tm = 0; tm < 4; ++tm) {
        int rowb = bm + wid * 64 + tm * 16 + quad * 4;
        #pragma unroll
        for (int r = 0; r < 4; ++r) {
            int row = rowb + r;
            if (row < M) {
                #pragma unroll
                for (int tn = 0; tn < 4; ++tn)
                    C[(size_t)row * Nc + bn + tn * 16 + mr] = f2bf(acc[tm][tn][r]);
            }
        }
    }
}

// ---------------- CSR gather + bias + relu ----------------
#define GMAXI 3   // supports Df <= 1536
__global__ __launch_bounds__(256) void gather_csr(
    const ushort* __restrict__ h, const int* __restrict__ off,
    const int* __restrict__ esrc, const float* __restrict__ ew,
    const float* __restrict__ bias, ushort* __restrict__ out_bf,
    float* __restrict__ out_f32, int Df, int wbf, int wf32)
{
    int n = blockIdx.x;
    int tid = threadIdx.x;
    const int half = Df >> 1;
    float2 acc[GMAXI];
    #pragma unroll
    for (int i = 0; i < GMAXI; ++i) acc[i] = make_float2(0.f, 0.f);

    int e0 = off[n], e1 = off[n + 1];
    for (int e = e0; e < e1; ++e) {
        int s = esrc[e];
        float w = ew[e];
        const ushort* row = h + (size_t)s * Df;
        #pragma unroll
        for (int i = 0; i < GMAXI; ++i) {
            int f2 = tid + i * 256;
            if (f2 < half) {
                ushort2 hv = *(const ushort2*)(row + f2 * 2);
                acc[i].x += w * bf2f(hv.x);
                acc[i].y += w * bf2f(hv.y);
            }
        }
    }
    #pragma unroll
    for (int i = 0; i < GMAXI; ++i) {
        int f2 = tid + i * 256;
        if (f2 < half) {
            int f = f2 * 2;
            float vx = fmaxf(acc[i].x + bias[f], 0.f);
            float vy = fmaxf(acc[i].y + bias[f + 1], 0.f);
            if (wbf) {
                ushort2 o; o.x = f2bf(vx); o.y = f2bf(vy);
                *(ushort2*)(out_bf + (size_t)n * Df + f) = o;
            }
            if (wf32)
                *(float2*)(out_f32 + (size_t)n * Df + f) = make_float2(vx, vy);
        }
    }
}

// ---------------- mean pool over graphs ----------------
__global__ void pool_accum(const float* __restrict__ x, const int* __restrict__ batch,
                           float* pool, float* cnt) {
    int n = blockIdx.x;
    int g = batch[n];
    if (threadIdx.x == 0) atomicAdd(&cnt[g], 1.0f);
    for (int f = threadIdx.x; f < 320; f += blockDim.x)
        atomicAdd(&pool[g * 320 + f], x[(size_t)n * 320 + f]);
}
__global__ void pool_div(float* pool, const float* __restrict__ cnt) {
    int g = blockIdx.x;
    float c = fmaxf(cnt[g], 1.0f);
    for (int f = threadIdx.x; f < 320; f += blockDim.x)
        pool[g * 320 + f] /= c;
}

// ---------------- MLP head: templated compile-time-K GEMM ----------------
template<int K, int RELU>
__global__ __launch_bounds__(256) void head_gemm(
    const float* __restrict__ in, int istride,
    const float* __restrict__ W, const float* __restrict__ b,
    float* __restrict__ out, int M, int Nc)
{
    int idx = blockIdx.x * blockDim.x + threadIdx.x;
    if (idx >= M * Nc) return;
    int m = idx / Nc, c = idx % Nc;
    const float* ip = in + (size_t)m * istride;
    const float* wp = W + c;
    float a0 = 0.f, a1 = 0.f, a2 = 0.f, a3 = 0.f;
    #pragma unroll
    for (int k = 0; k < K; k += 4) {
        float4 v = *(const float4*)(ip + k);
        a0 += v.x * wp[(size_t)(k + 0) * Nc];
        a1 += v.y * wp[(size_t)(k + 1) * Nc];
        a2 += v.z * wp[(size_t)(k + 2) * Nc];
        a3 += v.w * wp[(size_t)(k + 3) * Nc];
    }
    float s = (a0 + a1) + (a2 + a3) + b[c];
    out[idx] = RELU ? fmaxf(s, 0.f) : s;
}

__global__ void concat_pad(const float* __restrict__ fp, const float* __restrict__ xt,
                           float* __restrict__ xc) {
    int idx = blockIdx.x * blockDim.x + threadIdx.x;
    if (idx >= NGRAPH * 208) return;
    int g = idx / 208, j = idx % 208;
    float v = 0.f;
    if (j < FPD) v = fp[g * FPD + j];
    else if (j < 193) v = xt[g * 128 + (j - FPD)];
    xc[idx] = v;
}
__global__ void pad_w(const float* __restrict__ Wf1, float* __restrict__ Wp) {
    int idx = blockIdx.x * blockDim.x + threadIdx.x;
    if (idx >= 208 * 1024) return;
    int k = idx / 1024;
    Wp[idx] = (k < 193) ? Wf1[idx] : 0.f;
}

__global__ __launch_bounds__(256) void head_out(
    const float* __restrict__ f2, const float* __restrict__ Wo,
    const float* __restrict__ bo, float* __restrict__ out)
{
    int m = blockIdx.x;
    int t = threadIdx.x;
    float2 v = *(const float2*)(f2 + (size_t)m * 512 + t * 2);
    float2 w = *(const float2*)(Wo + t * 2);
    float s = v.x * w.x + v.y * w.y;
    #pragma unroll
    for (int o = 32; o > 0; o >>= 1) s += __shfl_down(s, o, 64);
    __shared__ float ps[4];
    if ((t & 63) == 0) ps[t >> 6] = s;
    __syncthreads();
    if (t == 0) out[m] = ps[0] + ps[1] + ps[2] + ps[3] + bo[0];
}

extern "C" void kernel_launch(void* const* d_in, const int* in_sizes, int n_in,
                              void* d_out, int out_size, void* d_ws, size_t ws_size,
                              hipStream_t stream) {
    const float* x    = (const float*)d_in[0];
    const int*   eidx = (const int*)d_in[1];
    const int*   batch= (const int*)d_in[2];
    const float* fp_x = (const float*)d_in[3];
    const float* W1 = (const float*)d_in[4];  const float* b1 = (const float*)d_in[5];
    const float* W2 = (const float*)d_in[6];  const float* b2 = (const float*)d_in[7];
    const float* W3 = (const float*)d_in[8];  const float* b3 = (const float*)d_in[9];
    const float* Wg1= (const float*)d_in[10]; const float* bg1= (const float*)d_in[11];
    const float* Wg2= (const float*)d_in[12]; const float* bg2= (const float*)d_in[13];
    const float* Wf1= (const float*)d_in[14]; const float* bf1= (const float*)d_in[15];
    const float* Wf2= (const float*)d_in[16]; const float* bf2= (const float*)d_in[17];
    const float* Wo = (const float*)d_in[18]; const float* bo = (const float*)d_in[19];
    float* out = (float*)d_out;

    const int* src = eidx;
    const int* dst = eidx + N_EDGES;

    // ---- workspace layout ----
    char* p = (char*)d_ws;
    float* dis   = (float*)p;  p += 20480 * 4;
    int*   cntI  = (int*)p;    p += 20480 * 4;
    int*   off   = (int*)p;    p += 20480 * 4;
    int*   cursor= (int*)p;    p += 20480 * 4;
    int*   esrc  = (int*)p;    p += 340992 * 4;
    float* ew    = (float*)p;  p += 340992 * 4;
    ushort* xbf  = (ushort*)p; p += (size_t)N_NODES * 1280 * 2;
    ushort* hbf  = (ushort*)p; p += (size_t)N_NODES * 1280 * 2;
    ushort* abf  = (ushort*)p; p += (size_t)N_NODES * 1280 * 2;
    float* a3f   = (float*)p;  p += (size_t)N_NODES * 320 * 4;
    ushort* Wt   = (ushort*)p; p += (size_t)1280 * 1280 * 2;
    float* pool  = (float*)p;  p += NGRAPH * 320 * 4;
    float* cntf  = (float*)p;  p += 256 * 4;
    float* m1    = (float*)p;  p += NGRAPH * 1024 * 4;
    float* m2    = (float*)p;  p += NGRAPH * 128 * 4;
    float* xc    = (float*)p;  p += NGRAPH * 208 * 4;
    float* f1    = (float*)p;  p += NGRAPH * 1024 * 4;
    float* f2    = (float*)p;  p += NGRAPH * 512 * 4;
    float* Wf1p  = (float*)p;  p += 208 * 1024 * 4;

    // ---- CSR build ----
    init_cnt<<<(N_NODES + 255) / 256, 256, 0, stream>>>(cntI);
    count_in<<<(N_EDGES + 255) / 256, 256, 0, stream>>>(dst, cntI);
    make_dis<<<(N_NODES + 255) / 256, 256, 0, stream>>>(cntI, dis);
    scan_offsets<<<1, 256, 0, stream>>>(cntI, off, cursor);
    fill_csr<<<(N_EDGES + N_NODES + 255) / 256, 256, 0, stream>>>(src, dst, dis, cursor, esrc, ew);

    // ---- layer 1 ----
    {
        long long ne = (long long)N_NODES * 1280;
        conv_f32_bf16<<<(unsigned)((ne / 4 + 255) / 256), 256, 0, stream>>>(x, xbf, ne);
        transpose_conv<<<dim3(1280 / 32, 1280 / 32), dim3(32, 8), 0, stream>>>(W1, Wt, 1280, 1280);
        dim3 g(1280 / 64, (N_NODES + 255) / 256);   // x = n (A-panel reuse), y = m
        gemm_bf16<<<g, 256, 0, stream>>>(xbf, Wt, hbf, N_NODES, 1280, 1280);
        gather_csr<<<N_NODES, 256, 0, stream>>>(hbf, off, esrc, ew, b1, abf, (float*)nullptr, 1280, 1, 0);
    }
    // ---- layer 2 ----
    {
        transpose_conv<<<dim3(1280 / 32, 640 / 32), dim3(32, 8), 0, stream>>>(W2, Wt, 1280, 640);
        dim3 g(640 / 64, (N_NODES + 255) / 256);
        gemm_bf16<<<g, 256, 0, stream>>>(abf, Wt, hbf, N_NODES, 1280, 640);
        gather_csr<<<N_NODES, 256, 0, stream>>>(hbf, off, esrc, ew, b2, abf, (float*)nullptr, 640, 1, 0);
    }
    // ---- layer 3 ----
    {
        transpose_conv<<<dim3(640 / 32, 320 / 32), dim3(32, 8), 0, stream>>>(W3, Wt, 640, 320);
        dim3 g(320 / 64, (N_NODES + 255) / 256);
        gemm_bf16<<<g, 256, 0, stream>>>(abf, Wt, hbf, N_NODES, 640, 320);
        gather_csr<<<N_NODES, 256, 0, stream>>>(hbf, off, esrc, ew, b3, (ushort*)nullptr, a3f, 320, 0, 1);
    }

    // ---- global mean pool ----
    {
        long long tot = NGRAPH * 320 + 256;
        zero_f32<<<(unsigned)((tot + 255) / 256), 256, 0, stream>>>(pool, tot);
        pool_accum<<<N_NODES, 256, 0, stream>>>(a3f, batch, pool, cntf);
        pool_div<<<NGRAPH, 256, 0, stream>>>(pool, cntf);
    }

    // ---- MLP head ----
    head_gemm<320, 1><<<(NGRAPH * 1024 + 255) / 256, 256, 0, stream>>>(pool, 320, Wg1, bg1, m1, NGRAPH, 1024);
    head_gemm<1024, 0><<<(NGRAPH * 128 + 255) / 256, 256, 0, stream>>>(m1, 1024, Wg2, bg2, m2, NGRAPH, 128);
    concat_pad<<<(NGRAPH * 208 + 255) / 256, 256, 0, stream>>>(fp_x, m2, xc);
    pad_w<<<(208 * 1024 + 255) / 256, 256, 0, stream>>>(Wf1, Wf1p);
    head_gemm<208, 1><<<(NGRAPH * 1024 + 255) / 256, 256, 0, stream>>>(xc, 208, Wf1p, bf1, f1, NGRAPH, 1024);
    head_gemm<1024, 1><<<(NGRAPH * 512 + 255) / 256, 256, 0, stream>>>(f1, 1024, Wf2, bf2, f2, NGRAPH, 512);
    head_out<<<NGRAPH, 256, 0, stream>>>(f2, Wo, bo, out);
}

// Round 6
// 1194.325 us; speedup vs baseline: 4.5834x; 1.1372x over previous
//
#include <hip/hip_runtime.h>
#include <hip/hip_bf16.h>

#define N_NODES 20000
#define N_EDGES 320000
#define NGRAPH  64
#define FPD     65

typedef __attribute__((ext_vector_type(8))) __bf16 bf16x8;
typedef __attribute__((ext_vector_type(4))) float floatx4;

__device__ inline float bf2f(ushort u) {
    union { unsigned int i; float f; } c; c.i = ((unsigned int)u) << 16; return c.f;
}
__device__ inline ushort f2bf(float v) {
    __hip_bfloat16 h = __float2bfloat16(v);
    return *(ushort*)&h;
}
// async global->LDS, 16 B per lane; LDS dest must be wave-uniform-base + lane*16
__device__ __forceinline__ void gld_lds16(const ushort* g, ushort* l) {
    __builtin_amdgcn_global_load_lds(
        (const __attribute__((address_space(1))) unsigned int*)g,
        (__attribute__((address_space(3))) unsigned int*)l,
        16, 0, 0);
}

// ---------------- CSR build ----------------
__global__ void init_cnt(int* cnt) {
    int i = blockIdx.x * blockDim.x + threadIdx.x;
    if (i < N_NODES) cnt[i] = 1;   // self-loop
}
__global__ void count_in(const int* __restrict__ dst, int* cnt) {
    int e = blockIdx.x * blockDim.x + threadIdx.x;
    if (e < N_EDGES) atomicAdd(&cnt[dst[e]], 1);
}
__global__ void make_dis(const int* __restrict__ cnt, float* dis) {
    int i = blockIdx.x * blockDim.x + threadIdx.x;
    if (i < N_NODES) dis[i] = rsqrtf((float)cnt[i]);
}
__global__ __launch_bounds__(256) void scan_offsets(const int* __restrict__ cnt,
                                                    int* __restrict__ off, int* __restrict__ cursor) {
    __shared__ int part[256];
    int t = threadIdx.x;
    const int chunk = (N_NODES + 255) / 256;
    int lo = t * chunk, hi = min(lo + chunk, N_NODES);
    int s = 0;
    for (int i = lo; i < hi; ++i) s += cnt[i];
    part[t] = s;
    __syncthreads();
    for (int d = 1; d < 256; d <<= 1) {
        int v = (t >= d) ? part[t - d] : 0;
        __syncthreads();
        part[t] += v;
        __syncthreads();
    }
    int base = part[t] - s;
    for (int i = lo; i < hi; ++i) {
        off[i] = base; cursor[i] = base;
        base += cnt[i];
    }
    if (t == 255) off[N_NODES] = part[255];
}
__global__ void fill_csr(const int* __restrict__ src, const int* __restrict__ dst,
                         const float* __restrict__ dis, int* cursor,
                         int* __restrict__ esrc, float* __restrict__ ew) {
    int e = blockIdx.x * blockDim.x + threadIdx.x;
    if (e >= N_EDGES + N_NODES) return;
    int s, d; float w;
    if (e < N_EDGES) { s = src[e]; d = dst[e]; w = dis[s] * dis[d]; }
    else { s = d = e - N_EDGES; w = dis[s] * dis[s]; }
    int pos = atomicAdd(&cursor[d], 1);
    esrc[pos] = s; ew[pos] = w;
}

// ---------------- utility ----------------
__global__ void zero_f32(float* p, long long n) {
    long long i = (long long)blockIdx.x * blockDim.x + threadIdx.x;
    if (i < n) p[i] = 0.0f;
}
__global__ void conv_f32_bf16(const float* __restrict__ in, ushort* __restrict__ out, long long n) {
    long long i = ((long long)blockIdx.x * blockDim.x + threadIdx.x) * 4;
    if (i >= n) return;
    float4 v = *(const float4*)(in + i);
    ushort4 o;
    o.x = f2bf(v.x); o.y = f2bf(v.y); o.z = f2bf(v.z); o.w = f2bf(v.w);
    *(ushort4*)(out + i) = o;
}
// W[K][Nc] f32 -> Wt[Nc][K] bf16
__global__ void transpose_conv(const float* __restrict__ W, ushort* __restrict__ Wt, int K, int Nc) {
    __shared__ float t[32][33];
    int k0 = blockIdx.x * 32, n0 = blockIdx.y * 32;
    int tx = threadIdx.x, ty = threadIdx.y;
    #pragma unroll
    for (int i = 0; i < 4; ++i)
        t[ty + i * 8][tx] = W[(size_t)(k0 + ty + i * 8) * Nc + n0 + tx];
    __syncthreads();
    #pragma unroll
    for (int i = 0; i < 4; ++i)
        Wt[(size_t)(n0 + ty + i * 8) * K + k0 + tx] = f2bf(t[tx][ty + i * 8]);
}

// ---------------- bf16 MFMA GEMM: C[M,Nc](bf16) = A[M,K] @ Bt[Nc,K]^T ----------------
// Tile 256(M) x 64(N) x 32(K). grid.x = n-tiles (A-panel L2 reuse), grid.y = m-tiles.
// Staging via global_load_lds width=16.
__global__ __launch_bounds__(256) void gemm_bf16(
    const ushort* __restrict__ A, const ushort* __restrict__ Bt,
    ushort* __restrict__ C, int M, int K, int Nc)
{
    __shared__ ushort As[256 * 32];
    __shared__ ushort Bs[64 * 32];
    const int tid = threadIdx.x;
    const int wid = tid >> 6, lane = tid & 63;
    const int quad = lane >> 4, mr = lane & 15;
    const int bn = blockIdx.x * 64, bm = blockIdx.y * 256;

    floatx4 acc[4][4];
    #pragma unroll
    for (int i = 0; i < 4; ++i)
        #pragma unroll
        for (int j = 0; j < 4; ++j)
            acc[i][j] = (floatx4){0.f, 0.f, 0.f, 0.f};

    const int ca0 = tid;
    const int cb  = tid;

    for (int k0 = 0; k0 < K; k0 += 32) {
        #pragma unroll
        for (int i = 0; i < 4; ++i) {
            int c = ca0 + i * 256;
            int row = c >> 2, q = c & 3;
            gld_lds16(A + (size_t)(bm + row) * K + k0 + q * 8, &As[c * 8]);
        }
        {
            int row = cb >> 2, q = cb & 3;
            gld_lds16(Bt + (size_t)(bn + row) * K + k0 + q * 8, &Bs[cb * 8]);
        }
        __syncthreads();

        bf16x8 af[4], bfv[4];
        #pragma unroll
        for (int t = 0; t < 4; ++t)
            af[t] = *(const bf16x8*)&As[(wid * 64 + t * 16 + mr) * 32 + quad * 8];
        #pragma unroll
        for (int t = 0; t < 4; ++t)
            bfv[t] = *(const bf16x8*)&Bs[(t * 16 + mr) * 32 + quad * 8];

        #pragma unroll
        for (int tm = 0; tm < 4; ++tm)
            #pragma unroll
            for (int tn = 0; tn < 4; ++tn)
                acc[tm][tn] = __builtin_amdgcn_mfma_f32_16x16x32_bf16(af[tm], bfv[tn], acc[tm][tn], 0, 0, 0);
        __syncthreads();
    }

    #pragma unroll
    for (int tm = 0; tm < 4; ++tm) {
        int rowb = bm + wid * 64 + tm * 16 + quad * 4;
        #pragma unroll
        for (int r = 0; r < 4; ++r) {
            int row = rowb + r;
            if (row < M) {
                #pragma unroll
                for (int tn = 0; tn < 4; ++tn)
                    C[(size_t)row * Nc + bn + tn * 16 + mr] = f2bf(acc[tm][tn][r]);
            }
        }
    }
}

// ---------------- CSR gather, 4-edge batched, ushort4 loads ----------------
// TPN threads per node (256 % TPN == 0). Tail edges duplicate row0 with w=0
// (duplicate loads hit L1 - nearly free). 4 independent row streams per iter
// -> 4x outstanding loads vs serial edge walk.
template<int DF, int TPN>
__global__ __launch_bounds__(256) void gather_csr4(
    const ushort* __restrict__ h, const int* __restrict__ off,
    const int* __restrict__ esrc, const float* __restrict__ ew,
    const float* __restrict__ bias, ushort* __restrict__ out_bf,
    float* __restrict__ out_f32, int wbf, int wf32)
{
    constexpr int NPB = 256 / TPN;       // nodes per block
    constexpr int H4  = DF / 4;          // ushort4 chunks per row
    constexpr int NC  = (H4 + TPN - 1) / TPN;
    int tid = threadIdx.x;
    int n = blockIdx.x * NPB + tid / TPN;
    int t = tid % TPN;
    if (n >= N_NODES) return;

    float4 acc[NC];
    #pragma unroll
    for (int c = 0; c < NC; ++c) acc[c] = make_float4(0.f, 0.f, 0.f, 0.f);

    int e0 = off[n], e1 = off[n + 1];
    for (int e = e0; e < e1; e += 4) {
        int s0 = esrc[e];  float w0 = ew[e];
        int s1 = s0, s2 = s0, s3 = s0;
        float w1 = 0.f, w2 = 0.f, w3 = 0.f;
        if (e + 1 < e1) { s1 = esrc[e + 1]; w1 = ew[e + 1]; }
        if (e + 2 < e1) { s2 = esrc[e + 2]; w2 = ew[e + 2]; }
        if (e + 3 < e1) { s3 = esrc[e + 3]; w3 = ew[e + 3]; }
        const ushort* r0 = h + (size_t)s0 * DF;
        const ushort* r1 = h + (size_t)s1 * DF;
        const ushort* r2 = h + (size_t)s2 * DF;
        const ushort* r3 = h + (size_t)s3 * DF;
        #pragma unroll
        for (int c = 0; c < NC; ++c) {
            int f4 = t + c * TPN;
            if (H4 % TPN == 0 || f4 < H4) {
                ushort4 v0 = *(const ushort4*)(r0 + f4 * 4);
                ushort4 v1 = *(const ushort4*)(r1 + f4 * 4);
                ushort4 v2 = *(const ushort4*)(r2 + f4 * 4);
                ushort4 v3 = *(const ushort4*)(r3 + f4 * 4);
                acc[c].x += w0 * bf2f(v0.x) + w1 * bf2f(v1.x) + w2 * bf2f(v2.x) + w3 * bf2f(v3.x);
                acc[c].y += w0 * bf2f(v0.y) + w1 * bf2f(v1.y) + w2 * bf2f(v2.y) + w3 * bf2f(v3.y);
                acc[c].z += w0 * bf2f(v0.z) + w1 * bf2f(v1.z) + w2 * bf2f(v2.z) + w3 * bf2f(v3.z);
                acc[c].w += w0 * bf2f(v0.w) + w1 * bf2f(v1.w) + w2 * bf2f(v2.w) + w3 * bf2f(v3.w);
            }
        }
    }

    #pragma unroll
    for (int c = 0; c < NC; ++c) {
        int f4 = t + c * TPN;
        if (H4 % TPN == 0 || f4 < H4) {
            float4 bv = *(const float4*)(bias + f4 * 4);
            float vx = fmaxf(acc[c].x + bv.x, 0.f);
            float vy = fmaxf(acc[c].y + bv.y, 0.f);
            float vz = fmaxf(acc[c].z + bv.z, 0.f);
            float vw = fmaxf(acc[c].w + bv.w, 0.f);
            if (wbf) {
                ushort4 o;
                o.x = f2bf(vx); o.y = f2bf(vy); o.z = f2bf(vz); o.w = f2bf(vw);
                *(ushort4*)(out_bf + (size_t)n * DF + f4 * 4) = o;
            }
            if (wf32)
                *(float4*)(out_f32 + (size_t)n * DF + f4 * 4) = make_float4(vx, vy, vz, vw);
        }
    }
}

// ---------------- mean pool over graphs ----------------
__global__ void pool_accum(const float* __restrict__ x, const int* __restrict__ batch,
                           float* pool, float* cnt) {
    int n = blockIdx.x;
    int g = batch[n];
    if (threadIdx.x == 0) atomicAdd(&cnt[g], 1.0f);
    for (int f = threadIdx.x; f < 320; f += blockDim.x)
        atomicAdd(&pool[g * 320 + f], x[(size_t)n * 320 + f]);
}
__global__ void pool_div(float* pool, const float* __restrict__ cnt) {
    int g = blockIdx.x;
    float c = fmaxf(cnt[g], 1.0f);
    for (int f = threadIdx.x; f < 320; f += blockDim.x)
        pool[g * 320 + f] /= c;
}

// ---------------- MLP head: templated compile-time-K GEMM ----------------
template<int K, int RELU>
__global__ __launch_bounds__(256) void head_gemm(
    const float* __restrict__ in, int istride,
    const float* __restrict__ W, const float* __restrict__ b,
    float* __restrict__ out, int M, int Nc)
{
    int idx = blockIdx.x * blockDim.x + threadIdx.x;
    if (idx >= M * Nc) return;
    int m = idx / Nc, c = idx % Nc;
    const float* ip = in + (size_t)m * istride;
    const float* wp = W + c;
    float a0 = 0.f, a1 = 0.f, a2 = 0.f, a3 = 0.f;
    #pragma unroll
    for (int k = 0; k < K; k += 4) {
        float4 v = *(const float4*)(ip + k);
        a0 += v.x * wp[(size_t)(k + 0) * Nc];
        a1 += v.y * wp[(size_t)(k + 1) * Nc];
        a2 += v.z * wp[(size_t)(k + 2) * Nc];
        a3 += v.w * wp[(size_t)(k + 3) * Nc];
    }
    float s = (a0 + a1) + (a2 + a3) + b[c];
    out[idx] = RELU ? fmaxf(s, 0.f) : s;
}

__global__ void concat_pad(const float* __restrict__ fp, const float* __restrict__ xt,
                           float* __restrict__ xc) {
    int idx = blockIdx.x * blockDim.x + threadIdx.x;
    if (idx >= NGRAPH * 208) return;
    int g = idx / 208, j = idx % 208;
    float v = 0.f;
    if (j < FPD) v = fp[g * FPD + j];
    else if (j < 193) v = xt[g * 128 + (j - FPD)];
    xc[idx] = v;
}
__global__ void pad_w(const float* __restrict__ Wf1, float* __restrict__ Wp) {
    int idx = blockIdx.x * blockDim.x + threadIdx.x;
    if (idx >= 208 * 1024) return;
    int k = idx / 1024;
    Wp[idx] = (k < 193) ? Wf1[idx] : 0.f;
}

__global__ __launch_bounds__(256) void head_out(
    const float* __restrict__ f2, const float* __restrict__ Wo,
    const float* __restrict__ bo, float* __restrict__ out)
{
    int m = blockIdx.x;
    int t = threadIdx.x;
    float2 v = *(const float2*)(f2 + (size_t)m * 512 + t * 2);
    float2 w = *(const float2*)(Wo + t * 2);
    float s = v.x * w.x + v.y * w.y;
    #pragma unroll
    for (int o = 32; o > 0; o >>= 1) s += __shfl_down(s, o, 64);
    __shared__ float ps[4];
    if ((t & 63) == 0) ps[t >> 6] = s;
    __syncthreads();
    if (t == 0) out[m] = ps[0] + ps[1] + ps[2] + ps[3] + bo[0];
}

extern "C" void kernel_launch(void* const* d_in, const int* in_sizes, int n_in,
                              void* d_out, int out_size, void* d_ws, size_t ws_size,
                              hipStream_t stream) {
    const float* x    = (const float*)d_in[0];
    const int*   eidx = (const int*)d_in[1];
    const int*   batch= (const int*)d_in[2];
    const float* fp_x = (const float*)d_in[3];
    const float* W1 = (const float*)d_in[4];  const float* b1 = (const float*)d_in[5];
    const float* W2 = (const float*)d_in[6];  const float* b2 = (const float*)d_in[7];
    const float* W3 = (const float*)d_in[8];  const float* b3 = (const float*)d_in[9];
    const float* Wg1= (const float*)d_in[10]; const float* bg1= (const float*)d_in[11];
    const float* Wg2= (const float*)d_in[12]; const float* bg2= (const float*)d_in[13];
    const float* Wf1= (const float*)d_in[14]; const float* bf1= (const float*)d_in[15];
    const float* Wf2= (const float*)d_in[16]; const float* bf2= (const float*)d_in[17];
    const float* Wo = (const float*)d_in[18]; const float* bo = (const float*)d_in[19];
    float* out = (float*)d_out;

    const int* src = eidx;
    const int* dst = eidx + N_EDGES;

    // ---- workspace layout ----
    char* p = (char*)d_ws;
    float* dis   = (float*)p;  p += 20480 * 4;
    int*   cntI  = (int*)p;    p += 20480 * 4;
    int*   off   = (int*)p;    p += 20480 * 4;
    int*   cursor= (int*)p;    p += 20480 * 4;
    int*   esrc  = (int*)p;    p += 340992 * 4;
    float* ew    = (float*)p;  p += 340992 * 4;
    ushort* xbf  = (ushort*)p; p += (size_t)N_NODES * 1280 * 2;
    ushort* hbf  = (ushort*)p; p += (size_t)N_NODES * 1280 * 2;
    ushort* abf  = (ushort*)p; p += (size_t)N_NODES * 1280 * 2;
    float* a3f   = (float*)p;  p += (size_t)N_NODES * 320 * 4;
    ushort* Wt   = (ushort*)p; p += (size_t)1280 * 1280 * 2;
    float* pool  = (float*)p;  p += NGRAPH * 320 * 4;
    float* cntf  = (float*)p;  p += 256 * 4;
    float* m1    = (float*)p;  p += NGRAPH * 1024 * 4;
    float* m2    = (float*)p;  p += NGRAPH * 128 * 4;
    float* xc    = (float*)p;  p += NGRAPH * 208 * 4;
    float* f1    = (float*)p;  p += NGRAPH * 1024 * 4;
    float* f2    = (float*)p;  p += NGRAPH * 512 * 4;
    float* Wf1p  = (float*)p;  p += 208 * 1024 * 4;

    // ---- CSR build ----
    init_cnt<<<(N_NODES + 255) / 256, 256, 0, stream>>>(cntI);
    count_in<<<(N_EDGES + 255) / 256, 256, 0, stream>>>(dst, cntI);
    make_dis<<<(N_NODES + 255) / 256, 256, 0, stream>>>(cntI, dis);
    scan_offsets<<<1, 256, 0, stream>>>(cntI, off, cursor);
    fill_csr<<<(N_EDGES + N_NODES + 255) / 256, 256, 0, stream>>>(src, dst, dis, cursor, esrc, ew);

    // ---- layer 1 ----
    {
        long long ne = (long long)N_NODES * 1280;
        conv_f32_bf16<<<(unsigned)((ne / 4 + 255) / 256), 256, 0, stream>>>(x, xbf, ne);
        transpose_conv<<<dim3(1280 / 32, 1280 / 32), dim3(32, 8), 0, stream>>>(W1, Wt, 1280, 1280);
        dim3 g(1280 / 64, (N_NODES + 255) / 256);
        gemm_bf16<<<g, 256, 0, stream>>>(xbf, Wt, hbf, N_NODES, 1280, 1280);
        gather_csr4<1280, 256><<<N_NODES, 256, 0, stream>>>(hbf, off, esrc, ew, b1, abf, (float*)nullptr, 1, 0);
    }
    // ---- layer 2 ----
    {
        transpose_conv<<<dim3(1280 / 32, 640 / 32), dim3(32, 8), 0, stream>>>(W2, Wt, 1280, 640);
        dim3 g(640 / 64, (N_NODES + 255) / 256);
        gemm_bf16<<<g, 256, 0, stream>>>(abf, Wt, hbf, N_NODES, 1280, 640);
        gather_csr4<640, 256><<<N_NODES, 256, 0, stream>>>(hbf, off, esrc, ew, b2, abf, (float*)nullptr, 1, 0);
    }
    // ---- layer 3 ----
    {
        transpose_conv<<<dim3(640 / 32, 320 / 32), dim3(32, 8), 0, stream>>>(W3, Wt, 640, 320);
        dim3 g(320 / 64, (N_NODES + 255) / 256);
        gemm_bf16<<<g, 256, 0, stream>>>(abf, Wt, hbf, N_NODES, 640, 320);
        gather_csr4<320, 128><<<(N_NODES + 1) / 2, 256, 0, stream>>>(hbf, off, esrc, ew, b3, (ushort*)nullptr, a3f, 0, 1);
    }

    // ---- global mean pool ----
    {
        long long tot = NGRAPH * 320 + 256;
        zero_f32<<<(unsigned)((tot + 255) / 256), 256, 0, stream>>>(pool, tot);
        pool_accum<<<N_NODES, 256, 0, stream>>>(a3f, batch, pool, cntf);
        pool_div<<<NGRAPH, 256, 0, stream>>>(pool, cntf);
    }

    // ---- MLP head ----
    head_gemm<320, 1><<<(NGRAPH * 1024 + 255) / 256, 256, 0, stream>>>(pool, 320, Wg1, bg1, m1, NGRAPH, 1024);
    head_gemm<1024, 0><<<(NGRAPH * 128 + 255) / 256, 256, 0, stream>>>(m1, 1024, Wg2, bg2, m2, NGRAPH, 128);
    concat_pad<<<(NGRAPH * 208 + 255) / 256, 256, 0, stream>>>(fp_x, m2, xc);
    pad_w<<<(208 * 1024 + 255) / 256, 256, 0, stream>>>(Wf1, Wf1p);
    head_gemm<208, 1><<<(NGRAPH * 1024 + 255) / 256, 256, 0, stream>>>(xc, 208, Wf1p, bf1, f1, NGRAPH, 1024);
    head_gemm<1024, 1><<<(NGRAPH * 512 + 255) / 256, 256, 0, stream>>>(f1, 1024, Wf2, bf2, f2, NGRAPH, 512);
    head_out<<<NGRAPH, 256, 0, stream>>>(f2, Wo, bo, out);
}

// Round 7
// 1070.842 us; speedup vs baseline: 5.1120x; 1.1153x over previous
//
#include <hip/hip_runtime.h>
#include <hip/hip_bf16.h>

#define N_NODES 20000
#define N_EDGES 320000
#define NGRAPH  64
#define FPD     65

typedef __attribute__((ext_vector_type(8))) __bf16 bf16x8;
typedef __attribute__((ext_vector_type(4))) float floatx4;

__device__ inline float bf2f(ushort u) {
    union { unsigned int i; float f; } c; c.i = ((unsigned int)u) << 16; return c.f;
}
__device__ inline ushort f2bf(float v) {
    __hip_bfloat16 h = __float2bfloat16(v);
    return *(ushort*)&h;
}
// async global->LDS, 16 B per lane; LDS dest must be wave-uniform-base + lane*16
__device__ __forceinline__ void gld_lds16(const ushort* g, ushort* l) {
    __builtin_amdgcn_global_load_lds(
        (const __attribute__((address_space(1))) unsigned int*)g,
        (__attribute__((address_space(3))) unsigned int*)l,
        16, 0, 0);
}

// ---------------- CSR build ----------------
__global__ void init_cnt(int* cnt) {
    int i = blockIdx.x * blockDim.x + threadIdx.x;
    if (i < N_NODES) cnt[i] = 1;   // self-loop
}
__global__ void count_in(const int* __restrict__ dst, int* cnt) {
    int e = blockIdx.x * blockDim.x + threadIdx.x;
    if (e < N_EDGES) atomicAdd(&cnt[dst[e]], 1);
}
__global__ void make_dis(const int* __restrict__ cnt, float* dis) {
    int i = blockIdx.x * blockDim.x + threadIdx.x;
    if (i < N_NODES) dis[i] = rsqrtf((float)cnt[i]);
}
__global__ __launch_bounds__(256) void scan_offsets(const int* __restrict__ cnt,
                                                    int* __restrict__ off, int* __restrict__ cursor) {
    __shared__ int part[256];
    int t = threadIdx.x;
    const int chunk = (N_NODES + 255) / 256;
    int lo = t * chunk, hi = min(lo + chunk, N_NODES);
    int s = 0;
    for (int i = lo; i < hi; ++i) s += cnt[i];
    part[t] = s;
    __syncthreads();
    for (int d = 1; d < 256; d <<= 1) {
        int v = (t >= d) ? part[t - d] : 0;
        __syncthreads();
        part[t] += v;
        __syncthreads();
    }
    int base = part[t] - s;
    for (int i = lo; i < hi; ++i) {
        off[i] = base; cursor[i] = base;
        base += cnt[i];
    }
    if (t == 255) off[N_NODES] = part[255];
}
__global__ void fill_csr(const int* __restrict__ src, const int* __restrict__ dst,
                         const float* __restrict__ dis, int* cursor,
                         int* __restrict__ esrc, float* __restrict__ ew) {
    int e = blockIdx.x * blockDim.x + threadIdx.x;
    if (e >= N_EDGES + N_NODES) return;
    int s, d; float w;
    if (e < N_EDGES) { s = src[e]; d = dst[e]; w = dis[s] * dis[d]; }
    else { s = d = e - N_EDGES; w = dis[s] * dis[s]; }
    int pos = atomicAdd(&cursor[d], 1);
    esrc[pos] = s; ew[pos] = w;
}

// ---------------- utility ----------------
__global__ void conv_f32_bf16(const float* __restrict__ in, ushort* __restrict__ out, long long n) {
    long long i = ((long long)blockIdx.x * blockDim.x + threadIdx.x) * 4;
    if (i >= n) return;
    float4 v = *(const float4*)(in + i);
    ushort4 o;
    o.x = f2bf(v.x); o.y = f2bf(v.y); o.z = f2bf(v.z); o.w = f2bf(v.w);
    *(ushort4*)(out + i) = o;
}
// W[K][Nc] f32 -> Wt[Nc][K] bf16
__global__ void transpose_conv(const float* __restrict__ W, ushort* __restrict__ Wt, int K, int Nc) {
    __shared__ float t[32][33];
    int k0 = blockIdx.x * 32, n0 = blockIdx.y * 32;
    int tx = threadIdx.x, ty = threadIdx.y;
    #pragma unroll
    for (int i = 0; i < 4; ++i)
        t[ty + i * 8][tx] = W[(size_t)(k0 + ty + i * 8) * Nc + n0 + tx];
    __syncthreads();
    #pragma unroll
    for (int i = 0; i < 4; ++i)
        Wt[(size_t)(n0 + ty + i * 8) * K + k0 + tx] = f2bf(t[tx][ty + i * 8]);
}

// ---------------- bf16 MFMA GEMM: C[M,Nc](bf16) = A[M,K] @ Bt[Nc,K]^T ----------------
__global__ __launch_bounds__(256) void gemm_bf16(
    const ushort* __restrict__ A, const ushort* __restrict__ Bt,
    ushort* __restrict__ C, int M, int K, int Nc)
{
    __shared__ ushort As[256 * 32];
    __shared__ ushort Bs[64 * 32];
    const int tid = threadIdx.x;
    const int wid = tid >> 6, lane = tid & 63;
    const int quad = lane >> 4, mr = lane & 15;
    const int bn = blockIdx.x * 64, bm = blockIdx.y * 256;

    floatx4 acc[4][4];
    #pragma unroll
    for (int i = 0; i < 4; ++i)
        #pragma unroll
        for (int j = 0; j < 4; ++j)
            acc[i][j] = (floatx4){0.f, 0.f, 0.f, 0.f};

    const int ca0 = tid;
    const int cb  = tid;

    for (int k0 = 0; k0 < K; k0 += 32) {
        #pragma unroll
        for (int i = 0; i < 4; ++i) {
            int c = ca0 + i * 256;
            int row = c >> 2, q = c & 3;
            gld_lds16(A + (size_t)(bm + row) * K + k0 + q * 8, &As[c * 8]);
        }
        {
            int row = cb >> 2, q = cb & 3;
            gld_lds16(Bt + (size_t)(bn + row) * K + k0 + q * 8, &Bs[cb * 8]);
        }
        __syncthreads();

        bf16x8 af[4], bfv[4];
        #pragma unroll
        for (int t = 0; t < 4; ++t)
            af[t] = *(const bf16x8*)&As[(wid * 64 + t * 16 + mr) * 32 + quad * 8];
        #pragma unroll
        for (int t = 0; t < 4; ++t)
            bfv[t] = *(const bf16x8*)&Bs[(t * 16 + mr) * 32 + quad * 8];

        #pragma unroll
        for (int tm = 0; tm < 4; ++tm)
            #pragma unroll
            for (int tn = 0; tn < 4; ++tn)
                acc[tm][tn] = __builtin_amdgcn_mfma_f32_16x16x32_bf16(af[tm], bfv[tn], acc[tm][tn], 0, 0, 0);
        __syncthreads();
    }

    #pragma unroll
    for (int tm = 0; tm < 4; ++tm) {
        int rowb = bm + wid * 64 + tm * 16 + quad * 4;
        #pragma unroll
        for (int r = 0; r < 4; ++r) {
            int row = rowb + r;
            if (row < M) {
                #pragma unroll
                for (int tn = 0; tn < 4; ++tn)
                    C[(size_t)row * Nc + bn + tn * 16 + mr] = f2bf(acc[tm][tn][r]);
            }
        }
    }
}

// ---------------- CSR gather, 4-edge batched, ushort4 loads ----------------
template<int DF, int TPN>
__global__ __launch_bounds__(256) void gather_csr4(
    const ushort* __restrict__ h, const int* __restrict__ off,
    const int* __restrict__ esrc, const float* __restrict__ ew,
    const float* __restrict__ bias, ushort* __restrict__ out_bf,
    float* __restrict__ out_f32, int wbf, int wf32)
{
    constexpr int NPB = 256 / TPN;
    constexpr int H4  = DF / 4;
    constexpr int NC  = (H4 + TPN - 1) / TPN;
    int tid = threadIdx.x;
    int n = blockIdx.x * NPB + tid / TPN;
    int t = tid % TPN;
    if (n >= N_NODES) return;

    float4 acc[NC];
    #pragma unroll
    for (int c = 0; c < NC; ++c) acc[c] = make_float4(0.f, 0.f, 0.f, 0.f);

    int e0 = off[n], e1 = off[n + 1];
    for (int e = e0; e < e1; e += 4) {
        int s0 = esrc[e];  float w0 = ew[e];
        int s1 = s0, s2 = s0, s3 = s0;
        float w1 = 0.f, w2 = 0.f, w3 = 0.f;
        if (e + 1 < e1) { s1 = esrc[e + 1]; w1 = ew[e + 1]; }
        if (e + 2 < e1) { s2 = esrc[e + 2]; w2 = ew[e + 2]; }
        if (e + 3 < e1) { s3 = esrc[e + 3]; w3 = ew[e + 3]; }
        const ushort* r0 = h + (size_t)s0 * DF;
        const ushort* r1 = h + (size_t)s1 * DF;
        const ushort* r2 = h + (size_t)s2 * DF;
        const ushort* r3 = h + (size_t)s3 * DF;
        #pragma unroll
        for (int c = 0; c < NC; ++c) {
            int f4 = t + c * TPN;
            if (H4 % TPN == 0 || f4 < H4) {
                ushort4 v0 = *(const ushort4*)(r0 + f4 * 4);
                ushort4 v1 = *(const ushort4*)(r1 + f4 * 4);
                ushort4 v2 = *(const ushort4*)(r2 + f4 * 4);
                ushort4 v3 = *(const ushort4*)(r3 + f4 * 4);
                acc[c].x += w0 * bf2f(v0.x) + w1 * bf2f(v1.x) + w2 * bf2f(v2.x) + w3 * bf2f(v3.x);
                acc[c].y += w0 * bf2f(v0.y) + w1 * bf2f(v1.y) + w2 * bf2f(v2.y) + w3 * bf2f(v3.y);
                acc[c].z += w0 * bf2f(v0.z) + w1 * bf2f(v1.z) + w2 * bf2f(v2.z) + w3 * bf2f(v3.z);
                acc[c].w += w0 * bf2f(v0.w) + w1 * bf2f(v1.w) + w2 * bf2f(v2.w) + w3 * bf2f(v3.w);
            }
        }
    }

    #pragma unroll
    for (int c = 0; c < NC; ++c) {
        int f4 = t + c * TPN;
        if (H4 % TPN == 0 || f4 < H4) {
            float4 bv = *(const float4*)(bias + f4 * 4);
            float vx = fmaxf(acc[c].x + bv.x, 0.f);
            float vy = fmaxf(acc[c].y + bv.y, 0.f);
            float vz = fmaxf(acc[c].z + bv.z, 0.f);
            float vw = fmaxf(acc[c].w + bv.w, 0.f);
            if (wbf) {
                ushort4 o;
                o.x = f2bf(vx); o.y = f2bf(vy); o.z = f2bf(vz); o.w = f2bf(vw);
                *(ushort4*)(out_bf + (size_t)n * DF + f4 * 4) = o;
            }
            if (wf32)
                *(float4*)(out_f32 + (size_t)n * DF + f4 * 4) = make_float4(vx, vy, vz, vw);
        }
    }
}

// ---------------- mean pool over graphs (batch is SORTED -> contiguous ranges) ----------------
// gstart[g] = first node of graph g; gstart[NGRAPH] = N. Handles empty graphs.
__global__ void graph_bounds(const int* __restrict__ batch, int* __restrict__ gstart) {
    int n = blockIdx.x * blockDim.x + threadIdx.x;
    if (n >= N_NODES) return;
    int b = batch[n];
    int bp = (n == 0) ? -1 : batch[n - 1];
    for (int g = bp + 1; g <= b; ++g) gstart[g] = n;
    if (n == N_NODES - 1)
        for (int g = b + 1; g <= NGRAPH; ++g) gstart[g] = N_NODES;
}
// one block per graph, 320 threads (= 5 waves), thread t owns feature t.
__global__ __launch_bounds__(320) void pool_graph(
    const float* __restrict__ x, const int* __restrict__ gstart, float* __restrict__ pool)
{
    int g = blockIdx.x;
    int t = threadIdx.x;
    int s = gstart[g], e = gstart[g + 1];
    float a0 = 0.f, a1 = 0.f, a2 = 0.f, a3 = 0.f;
    int n = s;
    for (; n + 3 < e; n += 4) {
        a0 += x[(size_t)(n + 0) * 320 + t];
        a1 += x[(size_t)(n + 1) * 320 + t];
        a2 += x[(size_t)(n + 2) * 320 + t];
        a3 += x[(size_t)(n + 3) * 320 + t];
    }
    for (; n < e; ++n) a0 += x[(size_t)n * 320 + t];
    float acc = (a0 + a1) + (a2 + a3);
    pool[g * 320 + t] = acc / fmaxf((float)(e - s), 1.0f);
}

// ---------------- MLP head: templated compile-time-K GEMM ----------------
template<int K, int RELU>
__global__ __launch_bounds__(256) void head_gemm(
    const float* __restrict__ in, int istride,
    const float* __restrict__ W, const float* __restrict__ b,
    float* __restrict__ out, int M, int Nc)
{
    int idx = blockIdx.x * blockDim.x + threadIdx.x;
    if (idx >= M * Nc) return;
    int m = idx / Nc, c = idx % Nc;
    const float* ip = in + (size_t)m * istride;
    const float* wp = W + c;
    float a0 = 0.f, a1 = 0.f, a2 = 0.f, a3 = 0.f;
    #pragma unroll
    for (int k = 0; k < K; k += 4) {
        float4 v = *(const float4*)(ip + k);
        a0 += v.x * wp[(size_t)(k + 0) * Nc];
        a1 += v.y * wp[(size_t)(k + 1) * Nc];
        a2 += v.z * wp[(size_t)(k + 2) * Nc];
        a3 += v.w * wp[(size_t)(k + 3) * Nc];
    }
    float s = (a0 + a1) + (a2 + a3) + b[c];
    out[idx] = RELU ? fmaxf(s, 0.f) : s;
}

__global__ void concat_pad(const float* __restrict__ fp, const float* __restrict__ xt,
                           float* __restrict__ xc) {
    int idx = blockIdx.x * blockDim.x + threadIdx.x;
    if (idx >= NGRAPH * 208) return;
    int g = idx / 208, j = idx % 208;
    float v = 0.f;
    if (j < FPD) v = fp[g * FPD + j];
    else if (j < 193) v = xt[g * 128 + (j - FPD)];
    xc[idx] = v;
}
__global__ void pad_w(const float* __restrict__ Wf1, float* __restrict__ Wp) {
    int idx = blockIdx.x * blockDim.x + threadIdx.x;
    if (idx >= 208 * 1024) return;
    int k = idx / 1024;
    Wp[idx] = (k < 193) ? Wf1[idx] : 0.f;
}

__global__ __launch_bounds__(256) void head_out(
    const float* __restrict__ f2, const float* __restrict__ Wo,
    const float* __restrict__ bo, float* __restrict__ out)
{
    int m = blockIdx.x;
    int t = threadIdx.x;
    float2 v = *(const float2*)(f2 + (size_t)m * 512 + t * 2);
    float2 w = *(const float2*)(Wo + t * 2);
    float s = v.x * w.x + v.y * w.y;
    #pragma unroll
    for (int o = 32; o > 0; o >>= 1) s += __shfl_down(s, o, 64);
    __shared__ float ps[4];
    if ((t & 63) == 0) ps[t >> 6] = s;
    __syncthreads();
    if (t == 0) out[m] = ps[0] + ps[1] + ps[2] + ps[3] + bo[0];
}

extern "C" void kernel_launch(void* const* d_in, const int* in_sizes, int n_in,
                              void* d_out, int out_size, void* d_ws, size_t ws_size,
                              hipStream_t stream) {
    const float* x    = (const float*)d_in[0];
    const int*   eidx = (const int*)d_in[1];
    const int*   batch= (const int*)d_in[2];
    const float* fp_x = (const float*)d_in[3];
    const float* W1 = (const float*)d_in[4];  const float* b1 = (const float*)d_in[5];
    const float* W2 = (const float*)d_in[6];  const float* b2 = (const float*)d_in[7];
    const float* W3 = (const float*)d_in[8];  const float* b3 = (const float*)d_in[9];
    const float* Wg1= (const float*)d_in[10]; const float* bg1= (const float*)d_in[11];
    const float* Wg2= (const float*)d_in[12]; const float* bg2= (const float*)d_in[13];
    const float* Wf1= (const float*)d_in[14]; const float* bf1= (const float*)d_in[15];
    const float* Wf2= (const float*)d_in[16]; const float* bf2= (const float*)d_in[17];
    const float* Wo = (const float*)d_in[18]; const float* bo = (const float*)d_in[19];
    float* out = (float*)d_out;

    const int* src = eidx;
    const int* dst = eidx + N_EDGES;

    // ---- workspace layout ----
    char* p = (char*)d_ws;
    float* dis   = (float*)p;  p += 20480 * 4;
    int*   cntI  = (int*)p;    p += 20480 * 4;
    int*   off   = (int*)p;    p += 20480 * 4;
    int*   cursor= (int*)p;    p += 20480 * 4;
    int*   gstart= (int*)p;    p += 128 * 4;
    int*   esrc  = (int*)p;    p += 340992 * 4;
    float* ew    = (float*)p;  p += 340992 * 4;
    ushort* xbf  = (ushort*)p; p += (size_t)N_NODES * 1280 * 2;
    ushort* hbf  = (ushort*)p; p += (size_t)N_NODES * 1280 * 2;
    ushort* abf  = (ushort*)p; p += (size_t)N_NODES * 1280 * 2;
    float* a3f   = (float*)p;  p += (size_t)N_NODES * 320 * 4;
    ushort* Wt   = (ushort*)p; p += (size_t)1280 * 1280 * 2;
    float* pool  = (float*)p;  p += NGRAPH * 320 * 4;
    float* m1    = (float*)p;  p += NGRAPH * 1024 * 4;
    float* m2    = (float*)p;  p += NGRAPH * 128 * 4;
    float* xc    = (float*)p;  p += NGRAPH * 208 * 4;
    float* f1    = (float*)p;  p += NGRAPH * 1024 * 4;
    float* f2    = (float*)p;  p += NGRAPH * 512 * 4;
    float* Wf1p  = (float*)p;  p += 208 * 1024 * 4;

    // ---- CSR build ----
    init_cnt<<<(N_NODES + 255) / 256, 256, 0, stream>>>(cntI);
    count_in<<<(N_EDGES + 255) / 256, 256, 0, stream>>>(dst, cntI);
    make_dis<<<(N_NODES + 255) / 256, 256, 0, stream>>>(cntI, dis);
    scan_offsets<<<1, 256, 0, stream>>>(cntI, off, cursor);
    fill_csr<<<(N_EDGES + N_NODES + 255) / 256, 256, 0, stream>>>(src, dst, dis, cursor, esrc, ew);
    graph_bounds<<<(N_NODES + 255) / 256, 256, 0, stream>>>(batch, gstart);

    // ---- layer 1 ----
    {
        long long ne = (long long)N_NODES * 1280;
        conv_f32_bf16<<<(unsigned)((ne / 4 + 255) / 256), 256, 0, stream>>>(x, xbf, ne);
        transpose_conv<<<dim3(1280 / 32, 1280 / 32), dim3(32, 8), 0, stream>>>(W1, Wt, 1280, 1280);
        dim3 g(1280 / 64, (N_NODES + 255) / 256);
        gemm_bf16<<<g, 256, 0, stream>>>(xbf, Wt, hbf, N_NODES, 1280, 1280);
        gather_csr4<1280, 256><<<N_NODES, 256, 0, stream>>>(hbf, off, esrc, ew, b1, abf, (float*)nullptr, 1, 0);
    }
    // ---- layer 2 ----
    {
        transpose_conv<<<dim3(1280 / 32, 640 / 32), dim3(32, 8), 0, stream>>>(W2, Wt, 1280, 640);
        dim3 g(640 / 64, (N_NODES + 255) / 256);
        gemm_bf16<<<g, 256, 0, stream>>>(abf, Wt, hbf, N_NODES, 1280, 640);
        gather_csr4<640, 256><<<N_NODES, 256, 0, stream>>>(hbf, off, esrc, ew, b2, abf, (float*)nullptr, 1, 0);
    }
    // ---- layer 3 ----
    {
        transpose_conv<<<dim3(640 / 32, 320 / 32), dim3(32, 8), 0, stream>>>(W3, Wt, 640, 320);
        dim3 g(320 / 64, (N_NODES + 255) / 256);
        gemm_bf16<<<g, 256, 0, stream>>>(abf, Wt, hbf, N_NODES, 640, 320);
        gather_csr4<320, 128><<<(N_NODES + 1) / 2, 256, 0, stream>>>(hbf, off, esrc, ew, b3, (ushort*)nullptr, a3f, 0, 1);
    }

    // ---- global mean pool (no atomics: batch sorted -> contiguous segments) ----
    pool_graph<<<NGRAPH, 320, 0, stream>>>(a3f, gstart, pool);

    // ---- MLP head ----
    head_gemm<320, 1><<<(NGRAPH * 1024 + 255) / 256, 256, 0, stream>>>(pool, 320, Wg1, bg1, m1, NGRAPH, 1024);
    head_gemm<1024, 0><<<(NGRAPH * 128 + 255) / 256, 256, 0, stream>>>(m1, 1024, Wg2, bg2, m2, NGRAPH, 128);
    concat_pad<<<(NGRAPH * 208 + 255) / 256, 256, 0, stream>>>(fp_x, m2, xc);
    pad_w<<<(208 * 1024 + 255) / 256, 256, 0, stream>>>(Wf1, Wf1p);
    head_gemm<208, 1><<<(NGRAPH * 1024 + 255) / 256, 256, 0, stream>>>(xc, 208, Wf1p, bf1, f1, NGRAPH, 1024);
    head_gemm<1024, 1><<<(NGRAPH * 512 + 255) / 256, 256, 0, stream>>>(f1, 1024, Wf2, bf2, f2, NGRAPH, 512);
    head_out<<<NGRAPH, 256, 0, stream>>>(f2, Wo, bo, out);
}

// Round 8
// 891.555 us; speedup vs baseline: 6.1400x; 1.2011x over previous
//
#include <hip/hip_runtime.h>
#include <hip/hip_bf16.h>

#define N_NODES 20000
#define N_EDGES 320000
#define NGRAPH  64
#define FPD     65

typedef __attribute__((ext_vector_type(8))) __bf16 bf16x8;
typedef __attribute__((ext_vector_type(4))) float floatx4;

__device__ inline float bf2f(ushort u) {
    union { unsigned int i; float f; } c; c.i = ((unsigned int)u) << 16; return c.f;
}
__device__ inline ushort f2bf(float v) {
    __hip_bfloat16 h = __float2bfloat16(v);
    return *(ushort*)&h;
}
// async global->LDS, 16 B per lane; LDS dest must be wave-uniform-base + lane*16
__device__ __forceinline__ void gld_lds16(const ushort* g, ushort* l) {
    __builtin_amdgcn_global_load_lds(
        (const __attribute__((address_space(1))) unsigned int*)g,
        (__attribute__((address_space(3))) unsigned int*)l,
        16, 0, 0);
}

// ---------------- CSR build ----------------
__global__ void init_cnt(int* cnt) {
    int i = blockIdx.x * blockDim.x + threadIdx.x;
    if (i < N_NODES) cnt[i] = 1;   // self-loop
}
__global__ void count_in(const int* __restrict__ dst, int* cnt) {
    int e = blockIdx.x * blockDim.x + threadIdx.x;
    if (e < N_EDGES) atomicAdd(&cnt[dst[e]], 1);
}
__global__ void make_dis(const int* __restrict__ cnt, float* dis) {
    int i = blockIdx.x * blockDim.x + threadIdx.x;
    if (i < N_NODES) dis[i] = rsqrtf((float)cnt[i]);
}
__global__ __launch_bounds__(256) void scan_offsets(const int* __restrict__ cnt,
                                                    int* __restrict__ off, int* __restrict__ cursor) {
    __shared__ int part[256];
    int t = threadIdx.x;
    const int chunk = (N_NODES + 255) / 256;
    int lo = t * chunk, hi = min(lo + chunk, N_NODES);
    int s = 0;
    for (int i = lo; i < hi; ++i) s += cnt[i];
    part[t] = s;
    __syncthreads();
    for (int d = 1; d < 256; d <<= 1) {
        int v = (t >= d) ? part[t - d] : 0;
        __syncthreads();
        part[t] += v;
        __syncthreads();
    }
    int base = part[t] - s;
    for (int i = lo; i < hi; ++i) {
        off[i] = base; cursor[i] = base;
        base += cnt[i];
    }
    if (t == 255) off[N_NODES] = part[255];
}
__global__ void fill_csr(const int* __restrict__ src, const int* __restrict__ dst,
                         const float* __restrict__ dis, int* cursor,
                         int* __restrict__ esrc, float* __restrict__ ew) {
    int e = blockIdx.x * blockDim.x + threadIdx.x;
    if (e >= N_EDGES + N_NODES) return;
    int s, d; float w;
    if (e < N_EDGES) { s = src[e]; d = dst[e]; w = dis[s] * dis[d]; }
    else { s = d = e - N_EDGES; w = dis[s] * dis[s]; }
    int pos = atomicAdd(&cursor[d], 1);
    esrc[pos] = s; ew[pos] = w;
}

// ---------------- utility ----------------
__global__ void conv_f32_bf16(const float* __restrict__ in, ushort* __restrict__ out, long long n) {
    long long i = ((long long)blockIdx.x * blockDim.x + threadIdx.x) * 4;
    if (i >= n) return;
    float4 v = *(const float4*)(in + i);
    ushort4 o;
    o.x = f2bf(v.x); o.y = f2bf(v.y); o.z = f2bf(v.z); o.w = f2bf(v.w);
    *(ushort4*)(out + i) = o;
}
// W[K][Nc] f32 -> Wt[Nc][K] bf16
__global__ void transpose_conv(const float* __restrict__ W, ushort* __restrict__ Wt, int K, int Nc) {
    __shared__ float t[32][33];
    int k0 = blockIdx.x * 32, n0 = blockIdx.y * 32;
    int tx = threadIdx.x, ty = threadIdx.y;
    #pragma unroll
    for (int i = 0; i < 4; ++i)
        t[ty + i * 8][tx] = W[(size_t)(k0 + ty + i * 8) * Nc + n0 + tx];
    __syncthreads();
    #pragma unroll
    for (int i = 0; i < 4; ++i)
        Wt[(size_t)(n0 + ty + i * 8) * K + k0 + tx] = f2bf(t[tx][ty + i * 8]);
}

// ---------------- bf16 MFMA GEMM: C[M,Nc](bf16) = A[M,K] @ Bt[Nc,K]^T ----------------
__global__ __launch_bounds__(256) void gemm_bf16(
    const ushort* __restrict__ A, const ushort* __restrict__ Bt,
    ushort* __restrict__ C, int M, int K, int Nc)
{
    __shared__ ushort As[256 * 32];
    __shared__ ushort Bs[64 * 32];
    const int tid = threadIdx.x;
    const int wid = tid >> 6, lane = tid & 63;
    const int quad = lane >> 4, mr = lane & 15;
    const int bn = blockIdx.x * 64, bm = blockIdx.y * 256;

    floatx4 acc[4][4];
    #pragma unroll
    for (int i = 0; i < 4; ++i)
        #pragma unroll
        for (int j = 0; j < 4; ++j)
            acc[i][j] = (floatx4){0.f, 0.f, 0.f, 0.f};

    const int ca0 = tid;
    const int cb  = tid;

    for (int k0 = 0; k0 < K; k0 += 32) {
        #pragma unroll
        for (int i = 0; i < 4; ++i) {
            int c = ca0 + i * 256;
            int row = c >> 2, q = c & 3;
            gld_lds16(A + (size_t)(bm + row) * K + k0 + q * 8, &As[c * 8]);
        }
        {
            int row = cb >> 2, q = cb & 3;
            gld_lds16(Bt + (size_t)(bn + row) * K + k0 + q * 8, &Bs[cb * 8]);
        }
        __syncthreads();

        bf16x8 af[4], bfv[4];
        #pragma unroll
        for (int t = 0; t < 4; ++t)
            af[t] = *(const bf16x8*)&As[(wid * 64 + t * 16 + mr) * 32 + quad * 8];
        #pragma unroll
        for (int t = 0; t < 4; ++t)
            bfv[t] = *(const bf16x8*)&Bs[(t * 16 + mr) * 32 + quad * 8];

        #pragma unroll
        for (int tm = 0; tm < 4; ++tm)
            #pragma unroll
            for (int tn = 0; tn < 4; ++tn)
                acc[tm][tn] = __builtin_amdgcn_mfma_f32_16x16x32_bf16(af[tm], bfv[tn], acc[tm][tn], 0, 0, 0);
        __syncthreads();
    }

    #pragma unroll
    for (int tm = 0; tm < 4; ++tm) {
        int rowb = bm + wid * 64 + tm * 16 + quad * 4;
        #pragma unroll
        for (int r = 0; r < 4; ++r) {
            int row = rowb + r;
            if (row < M) {
                #pragma unroll
                for (int tn = 0; tn < 4; ++tn)
                    C[(size_t)row * Nc + bn + tn * 16 + mr] = f2bf(acc[tm][tn][r]);
            }
        }
    }
}

// ---------------- CSR gather, 4-edge batched, ushort4 loads ----------------
template<int DF, int TPN>
__global__ __launch_bounds__(256) void gather_csr4(
    const ushort* __restrict__ h, const int* __restrict__ off,
    const int* __restrict__ esrc, const float* __restrict__ ew,
    const float* __restrict__ bias, ushort* __restrict__ out_bf,
    float* __restrict__ out_f32, int wbf, int wf32)
{
    constexpr int NPB = 256 / TPN;
    constexpr int H4  = DF / 4;
    constexpr int NC  = (H4 + TPN - 1) / TPN;
    int tid = threadIdx.x;
    int n = blockIdx.x * NPB + tid / TPN;
    int t = tid % TPN;
    if (n >= N_NODES) return;

    float4 acc[NC];
    #pragma unroll
    for (int c = 0; c < NC; ++c) acc[c] = make_float4(0.f, 0.f, 0.f, 0.f);

    int e0 = off[n], e1 = off[n + 1];
    for (int e = e0; e < e1; e += 4) {
        int s0 = esrc[e];  float w0 = ew[e];
        int s1 = s0, s2 = s0, s3 = s0;
        float w1 = 0.f, w2 = 0.f, w3 = 0.f;
        if (e + 1 < e1) { s1 = esrc[e + 1]; w1 = ew[e + 1]; }
        if (e + 2 < e1) { s2 = esrc[e + 2]; w2 = ew[e + 2]; }
        if (e + 3 < e1) { s3 = esrc[e + 3]; w3 = ew[e + 3]; }
        const ushort* r0 = h + (size_t)s0 * DF;
        const ushort* r1 = h + (size_t)s1 * DF;
        const ushort* r2 = h + (size_t)s2 * DF;
        const ushort* r3 = h + (size_t)s3 * DF;
        #pragma unroll
        for (int c = 0; c < NC; ++c) {
            int f4 = t + c * TPN;
            if (H4 % TPN == 0 || f4 < H4) {
                ushort4 v0 = *(const ushort4*)(r0 + f4 * 4);
                ushort4 v1 = *(const ushort4*)(r1 + f4 * 4);
                ushort4 v2 = *(const ushort4*)(r2 + f4 * 4);
                ushort4 v3 = *(const ushort4*)(r3 + f4 * 4);
                acc[c].x += w0 * bf2f(v0.x) + w1 * bf2f(v1.x) + w2 * bf2f(v2.x) + w3 * bf2f(v3.x);
                acc[c].y += w0 * bf2f(v0.y) + w1 * bf2f(v1.y) + w2 * bf2f(v2.y) + w3 * bf2f(v3.y);
                acc[c].z += w0 * bf2f(v0.z) + w1 * bf2f(v1.z) + w2 * bf2f(v2.z) + w3 * bf2f(v3.z);
                acc[c].w += w0 * bf2f(v0.w) + w1 * bf2f(v1.w) + w2 * bf2f(v2.w) + w3 * bf2f(v3.w);
            }
        }
    }

    #pragma unroll
    for (int c = 0; c < NC; ++c) {
        int f4 = t + c * TPN;
        if (H4 % TPN == 0 || f4 < H4) {
            float4 bv = *(const float4*)(bias + f4 * 4);
            float vx = fmaxf(acc[c].x + bv.x, 0.f);
            float vy = fmaxf(acc[c].y + bv.y, 0.f);
            float vz = fmaxf(acc[c].z + bv.z, 0.f);
            float vw = fmaxf(acc[c].w + bv.w, 0.f);
            if (wbf) {
                ushort4 o;
                o.x = f2bf(vx); o.y = f2bf(vy); o.z = f2bf(vz); o.w = f2bf(vw);
                *(ushort4*)(out_bf + (size_t)n * DF + f4 * 4) = o;
            }
            if (wf32)
                *(float4*)(out_f32 + (size_t)n * DF + f4 * 4) = make_float4(vx, vy, vz, vw);
        }
    }
}

// ---------------- mean pool over graphs (batch sorted -> contiguous ranges) ----------------
__global__ void graph_bounds(const int* __restrict__ batch, int* __restrict__ gstart) {
    int n = blockIdx.x * blockDim.x + threadIdx.x;
    if (n >= N_NODES) return;
    int b = batch[n];
    int bp = (n == 0) ? -1 : batch[n - 1];
    for (int g = bp + 1; g <= b; ++g) gstart[g] = n;
    if (n == N_NODES - 1)
        for (int g = b + 1; g <= NGRAPH; ++g) gstart[g] = N_NODES;
}
__global__ __launch_bounds__(320) void pool_graph(
    const float* __restrict__ x, const int* __restrict__ gstart, float* __restrict__ pool)
{
    int g = blockIdx.x;
    int t = threadIdx.x;
    int s = gstart[g], e = gstart[g + 1];
    float a0 = 0.f, a1 = 0.f, a2 = 0.f, a3 = 0.f;
    int n = s;
    for (; n + 3 < e; n += 4) {
        a0 += x[(size_t)(n + 0) * 320 + t];
        a1 += x[(size_t)(n + 1) * 320 + t];
        a2 += x[(size_t)(n + 2) * 320 + t];
        a3 += x[(size_t)(n + 3) * 320 + t];
    }
    for (; n < e; ++n) a0 += x[(size_t)n * 320 + t];
    float acc = (a0 + a1) + (a2 + a3);
    pool[g * 320 + t] = acc / fmaxf((float)(e - s), 1.0f);
}

// ---------------- MLP head: split-K GEMM ----------------
// SPLIT lanes per output (adjacent in wave), each covers K/SPLIT, shfl_xor reduce.
// K/SPLIT must be divisible by 4.
template<int K, int SPLIT, int RELU>
__global__ __launch_bounds__(256) void head_gemm_sk(
    const float* __restrict__ in, int istride,
    const float* __restrict__ W, const float* __restrict__ b,
    float* __restrict__ out, int M, int Nc)
{
    constexpr int KQ = K / SPLIT;
    int idx = blockIdx.x * blockDim.x + threadIdx.x;
    int oi = idx / SPLIT, r = idx % SPLIT;
    if (oi >= M * Nc) return;
    int m = oi / Nc, c = oi % Nc;
    const float* ip = in + (size_t)m * istride + r * KQ;
    const float* wp = W + (size_t)r * KQ * Nc + c;
    float a0 = 0.f, a1 = 0.f, a2 = 0.f, a3 = 0.f;
    #pragma unroll
    for (int k = 0; k < KQ; k += 4) {
        float4 v = *(const float4*)(ip + k);
        a0 += v.x * wp[(size_t)(k + 0) * Nc];
        a1 += v.y * wp[(size_t)(k + 1) * Nc];
        a2 += v.z * wp[(size_t)(k + 2) * Nc];
        a3 += v.w * wp[(size_t)(k + 3) * Nc];
    }
    float s = (a0 + a1) + (a2 + a3);
    #pragma unroll
    for (int o = 1; o < SPLIT; o <<= 1) s += __shfl_xor(s, o, 64);
    if (r == 0) {
        s += b[c];
        out[oi] = RELU ? fmaxf(s, 0.f) : s;
    }
}

__global__ void concat_pad(const float* __restrict__ fp, const float* __restrict__ xt,
                           float* __restrict__ xc) {
    int idx = blockIdx.x * blockDim.x + threadIdx.x;
    if (idx >= NGRAPH * 208) return;
    int g = idx / 208, j = idx % 208;
    float v = 0.f;
    if (j < FPD) v = fp[g * FPD + j];
    else if (j < 193) v = xt[g * 128 + (j - FPD)];
    xc[idx] = v;
}
__global__ void pad_w(const float* __restrict__ Wf1, float* __restrict__ Wp) {
    int idx = blockIdx.x * blockDim.x + threadIdx.x;
    if (idx >= 208 * 1024) return;
    int k = idx / 1024;
    Wp[idx] = (k < 193) ? Wf1[idx] : 0.f;
}

__global__ __launch_bounds__(256) void head_out(
    const float* __restrict__ f2, const float* __restrict__ Wo,
    const float* __restrict__ bo, float* __restrict__ out)
{
    int m = blockIdx.x;
    int t = threadIdx.x;
    float2 v = *(const float2*)(f2 + (size_t)m * 512 + t * 2);
    float2 w = *(const float2*)(Wo + t * 2);
    float s = v.x * w.x + v.y * w.y;
    #pragma unroll
    for (int o = 32; o > 0; o >>= 1) s += __shfl_down(s, o, 64);
    __shared__ float ps[4];
    if ((t & 63) == 0) ps[t >> 6] = s;
    __syncthreads();
    if (t == 0) out[m] = ps[0] + ps[1] + ps[2] + ps[3] + bo[0];
}

extern "C" void kernel_launch(void* const* d_in, const int* in_sizes, int n_in,
                              void* d_out, int out_size, void* d_ws, size_t ws_size,
                              hipStream_t stream) {
    const float* x    = (const float*)d_in[0];
    const int*   eidx = (const int*)d_in[1];
    const int*   batch= (const int*)d_in[2];
    const float* fp_x = (const float*)d_in[3];
    const float* W1 = (const float*)d_in[4];  const float* b1 = (const float*)d_in[5];
    const float* W2 = (const float*)d_in[6];  const float* b2 = (const float*)d_in[7];
    const float* W3 = (const float*)d_in[8];  const float* b3 = (const float*)d_in[9];
    const float* Wg1= (const float*)d_in[10]; const float* bg1= (const float*)d_in[11];
    const float* Wg2= (const float*)d_in[12]; const float* bg2= (const float*)d_in[13];
    const float* Wf1= (const float*)d_in[14]; const float* bf1= (const float*)d_in[15];
    const float* Wf2= (const float*)d_in[16]; const float* bf2= (const float*)d_in[17];
    const float* Wo = (const float*)d_in[18]; const float* bo = (const float*)d_in[19];
    float* out = (float*)d_out;

    const int* src = eidx;
    const int* dst = eidx + N_EDGES;

    // ---- workspace layout ----
    char* p = (char*)d_ws;
    float* dis   = (float*)p;  p += 20480 * 4;
    int*   cntI  = (int*)p;    p += 20480 * 4;
    int*   off   = (int*)p;    p += 20480 * 4;
    int*   cursor= (int*)p;    p += 20480 * 4;
    int*   gstart= (int*)p;    p += 128 * 4;
    int*   esrc  = (int*)p;    p += 340992 * 4;
    float* ew    = (float*)p;  p += 340992 * 4;
    ushort* xbf  = (ushort*)p; p += (size_t)N_NODES * 1280 * 2;
    ushort* hbf  = (ushort*)p; p += (size_t)N_NODES * 1280 * 2;
    ushort* abf  = (ushort*)p; p += (size_t)N_NODES * 1280 * 2;
    float* a3f   = (float*)p;  p += (size_t)N_NODES * 320 * 4;
    ushort* Wt   = (ushort*)p; p += (size_t)1280 * 1280 * 2;
    float* pool  = (float*)p;  p += NGRAPH * 320 * 4;
    float* m1    = (float*)p;  p += NGRAPH * 1024 * 4;
    float* m2    = (float*)p;  p += NGRAPH * 128 * 4;
    float* xc    = (float*)p;  p += NGRAPH * 208 * 4;
    float* f1    = (float*)p;  p += NGRAPH * 1024 * 4;
    float* f2    = (float*)p;  p += NGRAPH * 512 * 4;
    float* Wf1p  = (float*)p;  p += 208 * 1024 * 4;

    // ---- CSR build ----
    init_cnt<<<(N_NODES + 255) / 256, 256, 0, stream>>>(cntI);
    count_in<<<(N_EDGES + 255) / 256, 256, 0, stream>>>(dst, cntI);
    make_dis<<<(N_NODES + 255) / 256, 256, 0, stream>>>(cntI, dis);
    scan_offsets<<<1, 256, 0, stream>>>(cntI, off, cursor);
    fill_csr<<<(N_EDGES + N_NODES + 255) / 256, 256, 0, stream>>>(src, dst, dis, cursor, esrc, ew);
    graph_bounds<<<(N_NODES + 255) / 256, 256, 0, stream>>>(batch, gstart);

    // ---- layer 1 ----
    {
        long long ne = (long long)N_NODES * 1280;
        conv_f32_bf16<<<(unsigned)((ne / 4 + 255) / 256), 256, 0, stream>>>(x, xbf, ne);
        transpose_conv<<<dim3(1280 / 32, 1280 / 32), dim3(32, 8), 0, stream>>>(W1, Wt, 1280, 1280);
        dim3 g(1280 / 64, (N_NODES + 255) / 256);
        gemm_bf16<<<g, 256, 0, stream>>>(xbf, Wt, hbf, N_NODES, 1280, 1280);
        gather_csr4<1280, 256><<<N_NODES, 256, 0, stream>>>(hbf, off, esrc, ew, b1, abf, (float*)nullptr, 1, 0);
    }
    // ---- layer 2 ----
    {
        transpose_conv<<<dim3(1280 / 32, 640 / 32), dim3(32, 8), 0, stream>>>(W2, Wt, 1280, 640);
        dim3 g(640 / 64, (N_NODES + 255) / 256);
        gemm_bf16<<<g, 256, 0, stream>>>(abf, Wt, hbf, N_NODES, 1280, 640);
        gather_csr4<640, 256><<<N_NODES, 256, 0, stream>>>(hbf, off, esrc, ew, b2, abf, (float*)nullptr, 1, 0);
    }
    // ---- layer 3 ----
    {
        transpose_conv<<<dim3(640 / 32, 320 / 32), dim3(32, 8), 0, stream>>>(W3, Wt, 640, 320);
        dim3 g(320 / 64, (N_NODES + 255) / 256);
        gemm_bf16<<<g, 256, 0, stream>>>(abf, Wt, hbf, N_NODES, 640, 320);
        gather_csr4<320, 128><<<(N_NODES + 1) / 2, 256, 0, stream>>>(hbf, off, esrc, ew, b3, (ushort*)nullptr, a3f, 0, 1);
    }

    // ---- global mean pool ----
    pool_graph<<<NGRAPH, 320, 0, stream>>>(a3f, gstart, pool);

    // ---- MLP head (split-K: SPLIT lanes per output) ----
    head_gemm_sk<320, 4, 1><<<(NGRAPH * 1024 * 4 + 255) / 256, 256, 0, stream>>>(pool, 320, Wg1, bg1, m1, NGRAPH, 1024);
    head_gemm_sk<1024, 8, 0><<<(NGRAPH * 128 * 8 + 255) / 256, 256, 0, stream>>>(m1, 1024, Wg2, bg2, m2, NGRAPH, 128);
    concat_pad<<<(NGRAPH * 208 + 255) / 256, 256, 0, stream>>>(fp_x, m2, xc);
    pad_w<<<(208 * 1024 + 255) / 256, 256, 0, stream>>>(Wf1, Wf1p);
    head_gemm_sk<208, 4, 1><<<(NGRAPH * 1024 * 4 + 255) / 256, 256, 0, stream>>>(xc, 208, Wf1p, bf1, f1, NGRAPH, 1024);
    head_gemm_sk<1024, 8, 1><<<(NGRAPH * 512 * 8 + 255) / 256, 256, 0, stream>>>(f1, 1024, Wf2, bf2, f2, NGRAPH, 512);
    head_out<<<NGRAPH, 256, 0, stream>>>(f2, Wo, bo, out);
}

// Round 9
// 858.697 us; speedup vs baseline: 6.3749x; 1.0383x over previous
//
#include <hip/hip_runtime.h>
#include <hip/hip_bf16.h>

#define N_NODES 20000
#define N_EDGES 320000
#define NGRAPH  64
#define FPD     65

typedef __attribute__((ext_vector_type(8))) __bf16 bf16x8;
typedef __attribute__((ext_vector_type(4))) float floatx4;

__device__ inline float bf2f(ushort u) {
    union { unsigned int i; float f; } c; c.i = ((unsigned int)u) << 16; return c.f;
}
__device__ inline ushort f2bf(float v) {
    __hip_bfloat16 h = __float2bfloat16(v);
    return *(ushort*)&h;
}
// async global->LDS, 16 B per lane; LDS dest must be wave-uniform-base + lane*16
__device__ __forceinline__ void gld_lds16(const ushort* g, ushort* l) {
    __builtin_amdgcn_global_load_lds(
        (const __attribute__((address_space(1))) unsigned int*)g,
        (__attribute__((address_space(3))) unsigned int*)l,
        16, 0, 0);
}

// ---------------- CSR build ----------------
__global__ void init_cnt(int* cnt) {
    int i = blockIdx.x * blockDim.x + threadIdx.x;
    if (i < N_NODES) cnt[i] = 1;   // self-loop
}
__global__ void count_in(const int* __restrict__ dst, int* cnt) {
    int e = blockIdx.x * blockDim.x + threadIdx.x;
    if (e < N_EDGES) atomicAdd(&cnt[dst[e]], 1);
}
__global__ void make_dis(const int* __restrict__ cnt, float* dis) {
    int i = blockIdx.x * blockDim.x + threadIdx.x;
    if (i < N_NODES) dis[i] = rsqrtf((float)cnt[i]);
}
__global__ __launch_bounds__(256) void scan_offsets(const int* __restrict__ cnt,
                                                    int* __restrict__ off, int* __restrict__ cursor) {
    __shared__ int part[256];
    int t = threadIdx.x;
    const int chunk = (N_NODES + 255) / 256;
    int lo = t * chunk, hi = min(lo + chunk, N_NODES);
    int s = 0;
    for (int i = lo; i < hi; ++i) s += cnt[i];
    part[t] = s;
    __syncthreads();
    for (int d = 1; d < 256; d <<= 1) {
        int v = (t >= d) ? part[t - d] : 0;
        __syncthreads();
        part[t] += v;
        __syncthreads();
    }
    int base = part[t] - s;
    for (int i = lo; i < hi; ++i) {
        off[i] = base; cursor[i] = base;
        base += cnt[i];
    }
    if (t == 255) off[N_NODES] = part[255];
}
__global__ void fill_csr(const int* __restrict__ src, const int* __restrict__ dst,
                         const float* __restrict__ dis, int* cursor,
                         int* __restrict__ esrc, float* __restrict__ ew) {
    int e = blockIdx.x * blockDim.x + threadIdx.x;
    if (e >= N_EDGES + N_NODES) return;
    int s, d; float w;
    if (e < N_EDGES) { s = src[e]; d = dst[e]; w = dis[s] * dis[d]; }
    else { s = d = e - N_EDGES; w = dis[s] * dis[s]; }
    int pos = atomicAdd(&cursor[d], 1);
    esrc[pos] = s; ew[pos] = w;
}

// ---------------- utility ----------------
__global__ void conv_f32_bf16(const float* __restrict__ in, ushort* __restrict__ out, long long n) {
    long long i = ((long long)blockIdx.x * blockDim.x + threadIdx.x) * 4;
    if (i >= n) return;
    float4 v = *(const float4*)(in + i);
    ushort4 o;
    o.x = f2bf(v.x); o.y = f2bf(v.y); o.z = f2bf(v.z); o.w = f2bf(v.w);
    *(ushort4*)(out + i) = o;
}
// W[K][Nc] f32 -> Wt[Nc][K] bf16
__global__ void transpose_conv(const float* __restrict__ W, ushort* __restrict__ Wt, int K, int Nc) {
    __shared__ float t[32][33];
    int k0 = blockIdx.x * 32, n0 = blockIdx.y * 32;
    int tx = threadIdx.x, ty = threadIdx.y;
    #pragma unroll
    for (int i = 0; i < 4; ++i)
        t[ty + i * 8][tx] = W[(size_t)(k0 + ty + i * 8) * Nc + n0 + tx];
    __syncthreads();
    #pragma unroll
    for (int i = 0; i < 4; ++i)
        Wt[(size_t)(n0 + ty + i * 8) * K + k0 + tx] = f2bf(t[tx][ty + i * 8]);
}

// ---------------- bf16 MFMA GEMM: C[M,Nc](bf16) = A[M,K] @ Bt[Nc,K]^T ----------------
// 1D grid padded to 8*chunk. XCD-aware remap: xcd = bi&7 (round-robin dispatch),
// tile = xcd*chunk + (bi>>3); tiles m-major/n-minor -> each XCD streams a contiguous
// run of m-panels through its own L2 exactly once.
// LDS XOR swizzle: position (row,col) holds global chunk (row, col^f(row)),
// f(r)=(r+(r>>2))&3 -> each quad's 16 lanes spread over all 8 bank-groups (2-way, free).
__device__ __forceinline__ int swz(int r) { return (r + (r >> 2)) & 3; }

__global__ __launch_bounds__(256) void gemm_bf16(
    const ushort* __restrict__ A, const ushort* __restrict__ Bt,
    ushort* __restrict__ C, int M, int K, int Nc, int nt, int total, int chunk)
{
    __shared__ ushort As[256 * 32];
    __shared__ ushort Bs[64 * 32];
    const int bi = blockIdx.x;
    const int tile = (bi & 7) * chunk + (bi >> 3);
    if (tile >= total) return;
    const int bm = (tile / nt) * 256, bn = (tile % nt) * 64;

    const int tid = threadIdx.x;
    const int wid = tid >> 6, lane = tid & 63;
    const int quad = lane >> 4, mr = lane & 15;

    floatx4 acc[4][4];
    #pragma unroll
    for (int i = 0; i < 4; ++i)
        #pragma unroll
        for (int j = 0; j < 4; ++j)
            acc[i][j] = (floatx4){0.f, 0.f, 0.f, 0.f};

    for (int k0 = 0; k0 < K; k0 += 32) {
        #pragma unroll
        for (int i = 0; i < 4; ++i) {
            int c = tid + i * 256;
            int row = c >> 2;
            int q = (c & 3) ^ swz(row);                  // permuted global source
            gld_lds16(A + (size_t)(bm + row) * K + k0 + q * 8, &As[c * 8]);
        }
        {
            int row = tid >> 2;
            int q = (tid & 3) ^ swz(row);
            gld_lds16(Bt + (size_t)(bn + row) * K + k0 + q * 8, &Bs[tid * 8]);
        }
        __syncthreads();

        bf16x8 af[4], bfv[4];
        #pragma unroll
        for (int t = 0; t < 4; ++t) {
            int ra = wid * 64 + t * 16 + mr;
            af[t] = *(const bf16x8*)&As[ra * 32 + (quad ^ swz(ra)) * 8];
        }
        #pragma unroll
        for (int t = 0; t < 4; ++t) {
            int rb = t * 16 + mr;
            bfv[t] = *(const bf16x8*)&Bs[rb * 32 + (quad ^ swz(rb)) * 8];
        }

        #pragma unroll
        for (int tm = 0; tm < 4; ++tm)
            #pragma unroll
            for (int tn = 0; tn < 4; ++tn)
                acc[tm][tn] = __builtin_amdgcn_mfma_f32_16x16x32_bf16(af[tm], bfv[tn], acc[tm][tn], 0, 0, 0);
        __syncthreads();
    }

    #pragma unroll
    for (int tm = 0; tm < 4; ++tm) {
        int rowb = bm + wid * 64 + tm * 16 + quad * 4;
        #pragma unroll
        for (int r = 0; r < 4; ++r) {
            int row = rowb + r;
            if (row < M) {
                #pragma unroll
                for (int tn = 0; tn < 4; ++tn)
                    C[(size_t)row * Nc + bn + tn * 16 + mr] = f2bf(acc[tm][tn][r]);
            }
        }
    }
}

static inline void launch_gemm(const ushort* A, const ushort* Bt, ushort* C,
                               int M, int K, int Nc, hipStream_t stream) {
    int mt = (M + 255) / 256, nt = Nc / 64;
    int total = mt * nt;
    int chunk = (total + 7) / 8;
    gemm_bf16<<<8 * chunk, 256, 0, stream>>>(A, Bt, C, M, K, Nc, nt, total, chunk);
}

// ---------------- CSR gather, 4-edge batched, ushort4 loads ----------------
template<int DF, int TPN>
__global__ __launch_bounds__(256) void gather_csr4(
    const ushort* __restrict__ h, const int* __restrict__ off,
    const int* __restrict__ esrc, const float* __restrict__ ew,
    const float* __restrict__ bias, ushort* __restrict__ out_bf,
    float* __restrict__ out_f32, int wbf, int wf32)
{
    constexpr int NPB = 256 / TPN;
    constexpr int H4  = DF / 4;
    constexpr int NC  = (H4 + TPN - 1) / TPN;
    int tid = threadIdx.x;
    int n = blockIdx.x * NPB + tid / TPN;
    int t = tid % TPN;
    if (n >= N_NODES) return;

    float4 acc[NC];
    #pragma unroll
    for (int c = 0; c < NC; ++c) acc[c] = make_float4(0.f, 0.f, 0.f, 0.f);

    int e0 = off[n], e1 = off[n + 1];
    for (int e = e0; e < e1; e += 4) {
        int s0 = esrc[e];  float w0 = ew[e];
        int s1 = s0, s2 = s0, s3 = s0;
        float w1 = 0.f, w2 = 0.f, w3 = 0.f;
        if (e + 1 < e1) { s1 = esrc[e + 1]; w1 = ew[e + 1]; }
        if (e + 2 < e1) { s2 = esrc[e + 2]; w2 = ew[e + 2]; }
        if (e + 3 < e1) { s3 = esrc[e + 3]; w3 = ew[e + 3]; }
        const ushort* r0 = h + (size_t)s0 * DF;
        const ushort* r1 = h + (size_t)s1 * DF;
        const ushort* r2 = h + (size_t)s2 * DF;
        const ushort* r3 = h + (size_t)s3 * DF;
        #pragma unroll
        for (int c = 0; c < NC; ++c) {
            int f4 = t + c * TPN;
            if (H4 % TPN == 0 || f4 < H4) {
                ushort4 v0 = *(const ushort4*)(r0 + f4 * 4);
                ushort4 v1 = *(const ushort4*)(r1 + f4 * 4);
                ushort4 v2 = *(const ushort4*)(r2 + f4 * 4);
                ushort4 v3 = *(const ushort4*)(r3 + f4 * 4);
                acc[c].x += w0 * bf2f(v0.x) + w1 * bf2f(v1.x) + w2 * bf2f(v2.x) + w3 * bf2f(v3.x);
                acc[c].y += w0 * bf2f(v0.y) + w1 * bf2f(v1.y) + w2 * bf2f(v2.y) + w3 * bf2f(v3.y);
                acc[c].z += w0 * bf2f(v0.z) + w1 * bf2f(v1.z) + w2 * bf2f(v2.z) + w3 * bf2f(v3.z);
                acc[c].w += w0 * bf2f(v0.w) + w1 * bf2f(v1.w) + w2 * bf2f(v2.w) + w3 * bf2f(v3.w);
            }
        }
    }

    #pragma unroll
    for (int c = 0; c < NC; ++c) {
        int f4 = t + c * TPN;
        if (H4 % TPN == 0 || f4 < H4) {
            float4 bv = *(const float4*)(bias + f4 * 4);
            float vx = fmaxf(acc[c].x + bv.x, 0.f);
            float vy = fmaxf(acc[c].y + bv.y, 0.f);
            float vz = fmaxf(acc[c].z + bv.z, 0.f);
            float vw = fmaxf(acc[c].w + bv.w, 0.f);
            if (wbf) {
                ushort4 o;
                o.x = f2bf(vx); o.y = f2bf(vy); o.z = f2bf(vz); o.w = f2bf(vw);
                *(ushort4*)(out_bf + (size_t)n * DF + f4 * 4) = o;
            }
            if (wf32)
                *(float4*)(out_f32 + (size_t)n * DF + f4 * 4) = make_float4(vx, vy, vz, vw);
        }
    }
}

// ---------------- mean pool over graphs (batch sorted -> contiguous ranges) ----------------
__global__ void graph_bounds(const int* __restrict__ batch, int* __restrict__ gstart) {
    int n = blockIdx.x * blockDim.x + threadIdx.x;
    if (n >= N_NODES) return;
    int b = batch[n];
    int bp = (n == 0) ? -1 : batch[n - 1];
    for (int g = bp + 1; g <= b; ++g) gstart[g] = n;
    if (n == N_NODES - 1)
        for (int g = b + 1; g <= NGRAPH; ++g) gstart[g] = N_NODES;
}
__global__ __launch_bounds__(320) void pool_graph(
    const float* __restrict__ x, const int* __restrict__ gstart, float* __restrict__ pool)
{
    int g = blockIdx.x;
    int t = threadIdx.x;
    int s = gstart[g], e = gstart[g + 1];
    float a0 = 0.f, a1 = 0.f, a2 = 0.f, a3 = 0.f;
    int n = s;
    for (; n + 3 < e; n += 4) {
        a0 += x[(size_t)(n + 0) * 320 + t];
        a1 += x[(size_t)(n + 1) * 320 + t];
        a2 += x[(size_t)(n + 2) * 320 + t];
        a3 += x[(size_t)(n + 3) * 320 + t];
    }
    for (; n < e; ++n) a0 += x[(size_t)n * 320 + t];
    float acc = (a0 + a1) + (a2 + a3);
    pool[g * 320 + t] = acc / fmaxf((float)(e - s), 1.0f);
}

// ---------------- MLP head: split-K GEMM ----------------
template<int K, int SPLIT, int RELU>
__global__ __launch_bounds__(256) void head_gemm_sk(
    const float* __restrict__ in, int istride,
    const float* __restrict__ W, const float* __restrict__ b,
    float* __restrict__ out, int M, int Nc)
{
    constexpr int KQ = K / SPLIT;
    int idx = blockIdx.x * blockDim.x + threadIdx.x;
    int oi = idx / SPLIT, r = idx % SPLIT;
    if (oi >= M * Nc) return;
    int m = oi / Nc, c = oi % Nc;
    const float* ip = in + (size_t)m * istride + r * KQ;
    const float* wp = W + (size_t)r * KQ * Nc + c;
    float a0 = 0.f, a1 = 0.f, a2 = 0.f, a3 = 0.f;
    #pragma unroll
    for (int k = 0; k < KQ; k += 4) {
        float4 v = *(const float4*)(ip + k);
        a0 += v.x * wp[(size_t)(k + 0) * Nc];
        a1 += v.y * wp[(size_t)(k + 1) * Nc];
        a2 += v.z * wp[(size_t)(k + 2) * Nc];
        a3 += v.w * wp[(size_t)(k + 3) * Nc];
    }
    float s = (a0 + a1) + (a2 + a3);
    #pragma unroll
    for (int o = 1; o < SPLIT; o <<= 1) s += __shfl_xor(s, o, 64);
    if (r == 0) {
        s += b[c];
        out[oi] = RELU ? fmaxf(s, 0.f) : s;
    }
}

__global__ void concat_pad(const float* __restrict__ fp, const float* __restrict__ xt,
                           float* __restrict__ xc) {
    int idx = blockIdx.x * blockDim.x + threadIdx.x;
    if (idx >= NGRAPH * 208) return;
    int g = idx / 208, j = idx % 208;
    float v = 0.f;
    if (j < FPD) v = fp[g * FPD + j];
    else if (j < 193) v = xt[g * 128 + (j - FPD)];
    xc[idx] = v;
}
__global__ void pad_w(const float* __restrict__ Wf1, float* __restrict__ Wp) {
    int idx = blockIdx.x * blockDim.x + threadIdx.x;
    if (idx >= 208 * 1024) return;
    int k = idx / 1024;
    Wp[idx] = (k < 193) ? Wf1[idx] : 0.f;
}

__global__ __launch_bounds__(256) void head_out(
    const float* __restrict__ f2, const float* __restrict__ Wo,
    const float* __restrict__ bo, float* __restrict__ out)
{
    int m = blockIdx.x;
    int t = threadIdx.x;
    float2 v = *(const float2*)(f2 + (size_t)m * 512 + t * 2);
    float2 w = *(const float2*)(Wo + t * 2);
    float s = v.x * w.x + v.y * w.y;
    #pragma unroll
    for (int o = 32; o > 0; o >>= 1) s += __shfl_down(s, o, 64);
    __shared__ float ps[4];
    if ((t & 63) == 0) ps[t >> 6] = s;
    __syncthreads();
    if (t == 0) out[m] = ps[0] + ps[1] + ps[2] + ps[3] + bo[0];
}

extern "C" void kernel_launch(void* const* d_in, const int* in_sizes, int n_in,
                              void* d_out, int out_size, void* d_ws, size_t ws_size,
                              hipStream_t stream) {
    const float* x    = (const float*)d_in[0];
    const int*   eidx = (const int*)d_in[1];
    const int*   batch= (const int*)d_in[2];
    const float* fp_x = (const float*)d_in[3];
    const float* W1 = (const float*)d_in[4];  const float* b1 = (const float*)d_in[5];
    const float* W2 = (const float*)d_in[6];  const float* b2 = (const float*)d_in[7];
    const float* W3 = (const float*)d_in[8];  const float* b3 = (const float*)d_in[9];
    const float* Wg1= (const float*)d_in[10]; const float* bg1= (const float*)d_in[11];
    const float* Wg2= (const float*)d_in[12]; const float* bg2= (const float*)d_in[13];
    const float* Wf1= (const float*)d_in[14]; const float* bf1= (const float*)d_in[15];
    const float* Wf2= (const float*)d_in[16]; const float* bf2= (const float*)d_in[17];
    const float* Wo = (const float*)d_in[18]; const float* bo = (const float*)d_in[19];
    float* out = (float*)d_out;

    const int* src = eidx;
    const int* dst = eidx + N_EDGES;

    // ---- workspace layout ----
    char* p = (char*)d_ws;
    float* dis   = (float*)p;  p += 20480 * 4;
    int*   cntI  = (int*)p;    p += 20480 * 4;
    int*   off   = (int*)p;    p += 20480 * 4;
    int*   cursor= (int*)p;    p += 20480 * 4;
    int*   gstart= (int*)p;    p += 128 * 4;
    int*   esrc  = (int*)p;    p += 340992 * 4;
    float* ew    = (float*)p;  p += 340992 * 4;
    ushort* xbf  = (ushort*)p; p += (size_t)N_NODES * 1280 * 2;
    ushort* hbf  = (ushort*)p; p += (size_t)N_NODES * 1280 * 2;
    ushort* abf  = (ushort*)p; p += (size_t)N_NODES * 1280 * 2;
    float* a3f   = (float*)p;  p += (size_t)N_NODES * 320 * 4;
    ushort* Wt   = (ushort*)p; p += (size_t)1280 * 1280 * 2;
    float* pool  = (float*)p;  p += NGRAPH * 320 * 4;
    float* m1    = (float*)p;  p += NGRAPH * 1024 * 4;
    float* m2    = (float*)p;  p += NGRAPH * 128 * 4;
    float* xc    = (float*)p;  p += NGRAPH * 208 * 4;
    float* f1    = (float*)p;  p += NGRAPH * 1024 * 4;
    float* f2    = (float*)p;  p += NGRAPH * 512 * 4;
    float* Wf1p  = (float*)p;  p += 208 * 1024 * 4;

    // ---- CSR build ----
    init_cnt<<<(N_NODES + 255) / 256, 256, 0, stream>>>(cntI);
    count_in<<<(N_EDGES + 255) / 256, 256, 0, stream>>>(dst, cntI);
    make_dis<<<(N_NODES + 255) / 256, 256, 0, stream>>>(cntI, dis);
    scan_offsets<<<1, 256, 0, stream>>>(cntI, off, cursor);
    fill_csr<<<(N_EDGES + N_NODES + 255) / 256, 256, 0, stream>>>(src, dst, dis, cursor, esrc, ew);
    graph_bounds<<<(N_NODES + 255) / 256, 256, 0, stream>>>(batch, gstart);

    // ---- layer 1 ----
    {
        long long ne = (long long)N_NODES * 1280;
        conv_f32_bf16<<<(unsigned)((ne / 4 + 255) / 256), 256, 0, stream>>>(x, xbf, ne);
        transpose_conv<<<dim3(1280 / 32, 1280 / 32), dim3(32, 8), 0, stream>>>(W1, Wt, 1280, 1280);
        launch_gemm(xbf, Wt, hbf, N_NODES, 1280, 1280, stream);
        gather_csr4<1280, 256><<<N_NODES, 256, 0, stream>>>(hbf, off, esrc, ew, b1, abf, (float*)nullptr, 1, 0);
    }
    // ---- layer 2 ----
    {
        transpose_conv<<<dim3(1280 / 32, 640 / 32), dim3(32, 8), 0, stream>>>(W2, Wt, 1280, 640);
        launch_gemm(abf, Wt, hbf, N_NODES, 1280, 640, stream);
        gather_csr4<640, 256><<<N_NODES, 256, 0, stream>>>(hbf, off, esrc, ew, b2, abf, (float*)nullptr, 1, 0);
    }
    // ---- layer 3 ----
    {
        transpose_conv<<<dim3(640 / 32, 320 / 32), dim3(32, 8), 0, stream>>>(W3, Wt, 640, 320);
        launch_gemm(abf, Wt, hbf, N_NODES, 640, 320, stream);
        gather_csr4<320, 128><<<(N_NODES + 1) / 2, 256, 0, stream>>>(hbf, off, esrc, ew, b3, (ushort*)nullptr, a3f, 0, 1);
    }

    // ---- global mean pool ----
    pool_graph<<<NGRAPH, 320, 0, stream>>>(a3f, gstart, pool);

    // ---- MLP head (split-K) ----
    head_gemm_sk<320, 4, 1><<<(NGRAPH * 1024 * 4 + 255) / 256, 256, 0, stream>>>(pool, 320, Wg1, bg1, m1, NGRAPH, 1024);
    head_gemm_sk<1024, 8, 0><<<(NGRAPH * 128 * 8 + 255) / 256, 256, 0, stream>>>(m1, 1024, Wg2, bg2, m2, NGRAPH, 128);
    concat_pad<<<(NGRAPH * 208 + 255) / 256, 256, 0, stream>>>(fp_x, m2, xc);
    pad_w<<<(208 * 1024 + 255) / 256, 256, 0, stream>>>(Wf1, Wf1p);
    head_gemm_sk<208, 4, 1><<<(NGRAPH * 1024 * 4 + 255) / 256, 256, 0, stream>>>(xc, 208, Wf1p, bf1, f1, NGRAPH, 1024);
    head_gemm_sk<1024, 8, 1><<<(NGRAPH * 512 * 8 + 255) / 256, 256, 0, stream>>>(f1, 1024, Wf2, bf2, f2, NGRAPH, 512);
    head_out<<<NGRAPH, 256, 0, stream>>>(f2, Wo, bo, out);
}